// Round 8
// baseline (436.174 us; speedup 1.0000x reference)
//
#include <hip/hip_runtime.h>

typedef __bf16 bf16_t;
typedef bf16_t bf16x8 __attribute__((ext_vector_type(8)));
typedef bf16_t bf16x4v __attribute__((ext_vector_type(4)));
typedef float f32x4 __attribute__((ext_vector_type(4)));

#define GLDS16(g, l) __builtin_amdgcn_global_load_lds( \
    (const __attribute__((address_space(1))) void*)(g), \
    (__attribute__((address_space(3))) void*)(l), 16, 0, 0)

// Problem constants
#define BB 2
#define SEQ 2048
#define DMODEL 2048
#define RDIM 512
#define NH 16
#define DNOPE 128
#define DROPE 64
#define DVDIM 128
#define MROWS 4096           // BB*SEQ
#define DQK 192              // DNOPE+DROPE

// ---------------- prep kernels ----------------

__global__ __launch_bounds__(256) void cast_x_kernel(const float* __restrict__ x,
                                                     bf16_t* __restrict__ xb) {
    int idx = blockIdx.x * 256 + threadIdx.x;
    float4 v = ((const float4*)x)[idx];
    bf16x4v o;
    o[0] = (bf16_t)v.x; o[1] = (bf16_t)v.y; o[2] = (bf16_t)v.z; o[3] = (bf16_t)v.w;
    ((bf16x4v*)xb)[idx] = o;
}

// W (K x N) f32 -> WT (N x K) bf16, tiled transpose
__global__ __launch_bounds__(256) void wtrans_kernel(const float* __restrict__ W,
                                                     bf16_t* __restrict__ WT,
                                                     int K, int N) {
    __shared__ float t[32][33];
    int n0 = blockIdx.x * 32, k0 = blockIdx.y * 32;
    int tx = threadIdx.x & 31, ty = threadIdx.x >> 5;  // ty 0..7
    #pragma unroll
    for (int i = 0; i < 4; ++i)
        t[ty + i*8][tx] = W[(size_t)(k0 + ty + i*8) * N + n0 + tx];
    __syncthreads();
    #pragma unroll
    for (int i = 0; i < 4; ++i)
        WT[(size_t)(n0 + ty + i*8) * K + k0 + tx] = (bf16_t)t[tx][ty + i*8];
}

__global__ __launch_bounds__(256) void rope_table_kernel(const float* __restrict__ freqs,
                                                         float* __restrict__ costab,
                                                         float* __restrict__ sintab) {
    int idx = blockIdx.x * 256 + threadIdx.x;   // SEQ*32 exact
    float f = freqs[idx];
    costab[idx] = cosf(f);
    sintab[idx] = sinf(f);
}

__global__ __launch_bounds__(256) void rmsnorm_kernel(const float* __restrict__ kvf,
                                                      const float* __restrict__ gkv,
                                                      bf16_t* __restrict__ kvb) {
    int m = blockIdx.x;
    int tid = threadIdx.x;
    const float* rowp = kvf + (size_t)m * RDIM;
    float2 v = *(const float2*)(rowp + tid * 2);
    float ss = v.x * v.x + v.y * v.y;
    #pragma unroll
    for (int d = 1; d < 64; d <<= 1) ss += __shfl_xor(ss, d, 64);
    __shared__ float red[4];
    if ((tid & 63) == 0) red[tid >> 6] = ss;
    __syncthreads();
    float tot = red[0] + red[1] + red[2] + red[3];
    float scale = rsqrtf(tot * (1.0f / RDIM) + 1e-6f);
    bf16_t* orow = kvb + (size_t)m * RDIM;
    orow[tid*2]     = (bf16_t)(v.x * scale * gkv[tid*2]);
    orow[tid*2 + 1] = (bf16_t)(v.y * scale * gkv[tid*2 + 1]);
}

// ---------------- GEMM: C(MxN) = A(MxK) * Bt(NxK)^T, bf16 in, OutT out --------
// 128x128 tile, BK=64, 4 waves (2x2), global_load_lds staging with XOR swizzle.
// EPI: 0 = plain store; 1 = kvout (rope cols n<3072 with n%192>=128);
//      2 = qfull (rope cols n>=2048). Rope pairs live in lanes (c, c^1).

template<typename OutT, int EPI>
__global__ __launch_bounds__(256, 2) void gemm_bt(const bf16_t* __restrict__ A,
                                                  const bf16_t* __restrict__ Bt,
                                                  OutT* __restrict__ C,
                                                  int M, int N, int K,
                                                  const float* __restrict__ costab,
                                                  const float* __restrict__ sintab) {
    __shared__ __align__(16) char ldsA[128 * 128];   // 128 rows x 128B (64 bf16)
    __shared__ __align__(16) char ldsB[128 * 128];
    int tid = threadIdx.x;
    int lane = tid & 63, wave = tid >> 6;
    int n0 = blockIdx.x * 128, m0 = blockIdx.y * 128;
    int wr = wave >> 1, wc = wave & 1;
    int g = lane >> 4, c = lane & 15;
    f32x4 acc[4][4] = {};

    int srow = tid >> 3;         // 0..31: row within 4KB staging slab
    int sch = tid & 7;           // chunk (16B) within 128B row

    int nkt = K >> 6;
    for (int kt = 0; kt < nkt; ++kt) {
        int k0 = kt << 6;
        #pragma unroll
        for (int j = 0; j < 4; ++j) {
            int row = j * 32 + srow;
            int csrc = sch ^ (row & 7);     // pre-swizzled source chunk
            const char* gA = (const char*)(A + (size_t)(m0 + row) * K + k0) + csrc * 16;
            const char* gB = (const char*)(Bt + (size_t)(n0 + row) * K + k0) + csrc * 16;
            char* lA = ldsA + j * 4096 + wave * 1024;
            char* lB = ldsB + j * 4096 + wave * 1024;
            GLDS16(gA, lA);
            GLDS16(gB, lB);
        }
        __syncthreads();
        #pragma unroll
        for (int kk = 0; kk < 2; ++kk) {
            int kb = kk * 64 + g * 16;      // byte offset within row
            bf16x8 aF[4], bF[4];
            #pragma unroll
            for (int m = 0; m < 4; ++m) {
                int row = wr * 64 + m * 16 + c;
                aF[m] = *(const bf16x8*)(ldsA + row * 128 + (kb ^ ((row & 7) << 4)));
            }
            #pragma unroll
            for (int n = 0; n < 4; ++n) {
                int row = wc * 64 + n * 16 + c;
                bF[n] = *(const bf16x8*)(ldsB + row * 128 + (kb ^ ((row & 7) << 4)));
            }
            #pragma unroll
            for (int m = 0; m < 4; ++m)
                #pragma unroll
                for (int n = 0; n < 4; ++n)
                    acc[m][n] = __builtin_amdgcn_mfma_f32_16x16x32_bf16(aF[m], bF[n], acc[m][n], 0, 0, 0);
        }
        __syncthreads();
    }
    // epilogue: C/D layout col=lane&15, row=(lane>>4)*4+i
    #pragma unroll
    for (int m = 0; m < 4; ++m) {
        int grow0 = m0 + wr * 64 + m * 16 + g * 4;
        #pragma unroll
        for (int n = 0; n < 4; ++n) {
            int gcol = n0 + wc * 64 + n * 16 + c;
            bool rope = false;
            int j = 0;
            if (EPI == 1) {
                rope = (gcol < 3072) && ((gcol % 192) >= 128);
                j = ((gcol % 192) - 128) >> 1;
            } else if (EPI == 2) {
                rope = (gcol >= 2048);
                j = ((gcol - 2048) & 63) >> 1;
            }
            if (EPI != 0 && rope) {
                bool even = (c & 1) == 0;
                #pragma unroll
                for (int i = 0; i < 4; ++i) {
                    float v = acc[m][n][i];
                    float pv = __shfl_xor(v, 1, 64);
                    int s = (grow0 + i) & (SEQ - 1);
                    float cs = costab[s * 32 + j], sn = sintab[s * 32 + j];
                    float o = even ? (v * cs - pv * sn) : (pv * sn + v * cs);
                    C[(size_t)(grow0 + i) * N + gcol] = (OutT)o;
                }
            } else {
                #pragma unroll
                for (int i = 0; i < 4; ++i)
                    C[(size_t)(grow0 + i) * N + gcol] = (OutT)acc[m][n][i];
            }
        }
    }
}

// v part of kvout -> vt [BH][128][SEQ]  (transposed for PV B-fragments)
__global__ __launch_bounds__(256) void pack_v_kernel(const bf16_t* __restrict__ kvout,
                                                     bf16_t* __restrict__ vt) {
    __shared__ bf16_t t[64][144];
    int blk = blockIdx.x;                 // 32 bh * 32 stiles
    int bh = blk >> 5, st = blk & 31;
    int s0 = st * 64;
    int b = bh >> 4, h = bh & 15;
    int tid = threadIdx.x;
    #pragma unroll
    for (int i = 0; i < 4; ++i) {
        int id = i * 256 + tid;           // 1024: 64 rows x 16 chunks
        int row = id >> 4, ch = id & 15;
        bf16x8 v = *(const bf16x8*)(kvout + (size_t)(b * SEQ + s0 + row) * 5120 + 3072 + h * 128 + ch * 8);
        *(bf16x8*)&t[row][ch * 8] = v;
    }
    __syncthreads();
    #pragma unroll
    for (int i = 0; i < 4; ++i) {
        int id = i * 256 + tid;           // 1024: 128 dv x 8 chunks
        int dv = id >> 3, sc = id & 7;
        bf16x8 v;
        #pragma unroll
        for (int jj = 0; jj < 8; ++jj) v[jj] = t[sc * 8 + jj][dv];
        *(bf16x8*)(vt + ((size_t)bh * 128 + dv) * SEQ + s0 + sc * 8) = v;
    }
}

// ---------------- flash attention v6 ----------------
// Q direct from qfull [M][3072]; K direct from kvout [M][5120] (h*192 slice);
// VT: [BH][128][S]; O: [M][2048] (col=h*128+dv).
// 512 blocks x 512 threads (8 waves). Each block: 128 q-rows; wave w owns rows
// q0+w*16..+15. KV tile 64 staged once per tile for all 8 waves. 2 blocks/CU,
// all resident; heavy/light pairing keeps per-CU work constant (36 tiles).
// Ones-column row-sum; defer-max (THR=8).

__global__ __launch_bounds__(512, 4) void attn_kernel(const bf16_t* __restrict__ Qf,
                                                      const bf16_t* __restrict__ KV,
                                                      const bf16_t* __restrict__ VT,
                                                      bf16_t* __restrict__ O) {
    __shared__ __align__(16) char ldsK[64 * 384];     // [64][192] bf16, swizzled content
    __shared__ __align__(16) char ldsV[128 * 128];    // [128 dv][64 s] bf16, swizzled content
    __shared__ __align__(16) char ldsP[8 * 16 * 176]; // per-wave [16][64+24pad] bf16
    int tid = threadIdx.x, lane = tid & 63, wave = tid >> 6;   // wave 0..7
    int g = lane >> 4, c = lane & 15;

    // XCD-aware mapping; slot<8 -> heavy (qt=15-slot), else light (qt=slot-8):
    // pair (bid, bid+256) sums to 36 tiles -> constant per-CU work.
    int bid = blockIdx.x;                // 0..511
    int xcd = bid & 7, rest = bid >> 3;  // rest 0..63
    int bh = xcd * 4 + (rest & 3);       // 0..31
    int slot = rest >> 2;                // 0..15
    int qt = (slot < 8) ? (15 - slot) : (slot - 8);
    int b = bh >> 4, h = bh & 15;
    int q0 = qt * 128;
    int nt = 2 * qt + 2;
    int tdiag = 2 * qt + (wave >> 2);    // this wave's diagonal tile

    const bf16_t* Kb = KV + (size_t)b * SEQ * 5120 + h * DQK;   // + s*5120
    const bf16_t* Vb = VT + (size_t)bh * 128 * SEQ;
    char* ldsPw = ldsP + wave * (16 * 176);

    // K staging map: 1536 chunks of 16B over 512 threads (3 issues);
    // source chunk XORed so linear LDS + swizzled read composes to identity.
    size_t soff[3];
    #pragma unroll
    for (int i2 = 0; i2 < 3; ++i2) {
        int id = i2 * 512 + tid;
        int row = id / 24, ch = id - row * 24;
        soff[i2] = (size_t)row * 10240 + (ch ^ (row & 7)) * 16;
    }
    // V staging map: 1024 chunks over 512 threads (2 issues).
    size_t voff[2];
    #pragma unroll
    for (int i2 = 0; i2 < 2; ++i2) {
        int id = i2 * 512 + tid;
        int row = id >> 3, ch = id & 7;
        voff[i2] = (size_t)row * (SEQ * 2) + (ch ^ (row & 7)) * 16;
    }
    const float sc = 0.0721687836f * 1.44269504f;   // 1/sqrt(192) * log2(e)

    bf16x8 vones;
    #pragma unroll
    for (int j = 0; j < 8; ++j) vones[j] = (bf16_t)1.0f;

    // Q fragments: lane (g,c) holds Q[row = q0+wave*16+c][k = kk*32 + g*8 + 0..7]
    bf16x8 qf[6];
    {
        int qrow = q0 + wave * 16 + c;
        const bf16_t* qn = Qf + (size_t)(b * SEQ + qrow) * 3072 + h * DNOPE + g * 8;
        #pragma unroll
        for (int kk = 0; kk < 4; ++kk) qf[kk] = *(const bf16x8*)(qn + kk * 32);
        const bf16_t* qr = Qf + (size_t)(b * SEQ + qrow) * 3072 + 2048 + h * DROPE + g * 8;
        qf[4] = *(const bf16x8*)(qr);
        qf[5] = *(const bf16x8*)(qr + 32);
    }
    float m_run[4];
    f32x4 accO[9] = {};                        // [8] = running row-sum (ones column)
    #pragma unroll
    for (int i = 0; i < 4; ++i) m_run[i] = -3.0e38f;

    #pragma unroll 1
    for (int t = 0; t < nt; ++t) {
        // stage K tile (24KB) + V tile (16KB) via global_load_lds (all 8 waves)
        const char* Kt = (const char*)(Kb + (size_t)t * 64 * 5120);
        #pragma unroll
        for (int i2 = 0; i2 < 3; ++i2)
            GLDS16(Kt + soff[i2], ldsK + i2 * 8192 + wave * 1024);
        const char* Vt = (const char*)Vb + (size_t)t * 128;   // t*64 elems
        #pragma unroll
        for (int i2 = 0; i2 < 2; ++i2)
            GLDS16(Vt + voff[i2], ldsV + i2 * 8192 + wave * 1024);
        __syncthreads();

        if (t <= tdiag) {                      // wave-uniform; no barrier inside
            bool diag = (t == tdiag);

            // QK^T: 16 q-rows x 64 k
            f32x4 accS[4] = {};
            __builtin_amdgcn_s_setprio(1);
            #pragma unroll
            for (int kk = 0; kk < 6; ++kk) {
                int kb = kk * 64 + g * 16;
                #pragma unroll
                for (int n = 0; n < 4; ++n) {
                    int row = n * 16 + c;
                    bf16x8 kf = *(const bf16x8*)(ldsK + row * 384 + (kb ^ ((row & 7) << 4)));
                    accS[n] = __builtin_amdgcn_mfma_f32_16x16x32_bf16(qf[kk], kf, accS[n], 0, 0, 0);
                }
            }
            __builtin_amdgcn_s_setprio(0);

            // scale + causal mask (diag tile: in-tile row offset = (wave&3)*16)
            #pragma unroll
            for (int n = 0; n < 4; ++n)
                #pragma unroll
                for (int i = 0; i < 4; ++i) {
                    float v = accS[n][i] * sc;
                    if (diag && (n * 16 + c > (wave & 3) * 16 + g * 4 + i)) v = -1e30f;
                    accS[n][i] = v;
                }
            // row max; sum comes free via ones-column MFMA
            float mx[4];
            #pragma unroll
            for (int i = 0; i < 4; ++i) {
                float m2 = fmaxf(fmaxf(accS[0][i], accS[1][i]), fmaxf(accS[2][i], accS[3][i]));
                #pragma unroll
                for (int d = 1; d < 16; d <<= 1) m2 = fmaxf(m2, __shfl_xor(m2, d, 64));
                mx[i] = m2;
            }
            bool nore = __all((mx[0] <= m_run[0] + 8.f) & (mx[1] <= m_run[1] + 8.f) &
                              (mx[2] <= m_run[2] + 8.f) & (mx[3] <= m_run[3] + 8.f));
            if (nore) {
                #pragma unroll
                for (int i = 0; i < 4; ++i)
                    #pragma unroll
                    for (int n = 0; n < 4; ++n)
                        accS[n][i] = exp2f(accS[n][i] - m_run[i]);
            } else {
                #pragma unroll
                for (int i = 0; i < 4; ++i) {
                    float mnew = fmaxf(m_run[i], mx[i]);
                    float alpha = exp2f(m_run[i] - mnew);
                    m_run[i] = mnew;
                    #pragma unroll
                    for (int n = 0; n < 4; ++n)
                        accS[n][i] = exp2f(accS[n][i] - mnew);
                    #pragma unroll
                    for (int n = 0; n < 9; ++n) accO[n][i] *= alpha;
                }
            }
            // P (C-frag) -> per-wave LDS -> A-frag
            #pragma unroll
            for (int n = 0; n < 4; ++n)
                #pragma unroll
                for (int i = 0; i < 4; ++i)
                    *(bf16_t*)(ldsPw + (g * 4 + i) * 176 + (n * 16 + c) * 2) = (bf16_t)accS[n][i];
            bf16x8 pf0 = *(const bf16x8*)(ldsPw + c * 176 + g * 16);
            bf16x8 pf1 = *(const bf16x8*)(ldsPw + c * 176 + 64 + g * 16);

            // PV: V from LDS (swizzled read), plus ones-column for row-sum
            __builtin_amdgcn_s_setprio(1);
            #pragma unroll
            for (int n = 0; n < 8; ++n) {
                int row = n * 16 + c;
                bf16x8 vf0 = *(const bf16x8*)(ldsV + row * 128 + ((g * 16) ^ ((c & 7) << 4)));
                bf16x8 vf1 = *(const bf16x8*)(ldsV + row * 128 + ((64 + g * 16) ^ ((c & 7) << 4)));
                accO[n] = __builtin_amdgcn_mfma_f32_16x16x32_bf16(pf0, vf0, accO[n], 0, 0, 0);
                accO[n] = __builtin_amdgcn_mfma_f32_16x16x32_bf16(pf1, vf1, accO[n], 0, 0, 0);
            }
            accO[8] = __builtin_amdgcn_mfma_f32_16x16x32_bf16(pf0, vones, accO[8], 0, 0, 0);
            accO[8] = __builtin_amdgcn_mfma_f32_16x16x32_bf16(pf1, vones, accO[8], 0, 0, 0);
            __builtin_amdgcn_s_setprio(0);
        }
        __syncthreads();   // all waves done with ldsK/ldsV before next stage
    }
    // write O, normalizing by the ones-column running sum
    float inv_l[4];
    #pragma unroll
    for (int i = 0; i < 4; ++i) inv_l[i] = 1.0f / accO[8][i];
    #pragma unroll
    for (int n = 0; n < 8; ++n) {
        int gcol = h * 128 + n * 16 + c;
        #pragma unroll
        for (int i = 0; i < 4; ++i) {
            int mrow = b * SEQ + q0 + wave * 16 + g * 4 + i;
            O[(size_t)mrow * 2048 + gcol] = (bf16_t)(accO[n][i] * inv_l[i]);
        }
    }
}

// ---------------- launch ----------------

extern "C" void kernel_launch(void* const* d_in, const int* in_sizes, int n_in,
                              void* d_out, int out_size, void* d_ws, size_t ws_size,
                              hipStream_t stream) {
    const float* x     = (const float*)d_in[0];
    const float* freqs = (const float*)d_in[1];
    const float* w_kv  = (const float*)d_in[2];
    const float* g_kv  = (const float*)d_in[3];
    const float* w_k   = (const float*)d_in[4];
    const float* w_v   = (const float*)d_in[5];
    const float* w_qn  = (const float*)d_in[6];
    const float* w_qr  = (const float*)d_in[7];
    const float* w_o   = (const float*)d_in[8];
    float* out = (float*)d_out;

    char* ws = (char*)d_ws;
    size_t off = 0;
    auto alloc = [&](size_t bytes) { char* p = ws + off; off += (bytes + 255) & ~(size_t)255; return p; };
    bf16_t* xb     = (bf16_t*)alloc((size_t)MROWS * DMODEL * 2);
    bf16_t* wkvT   = (bf16_t*)alloc((size_t)RDIM * DMODEL * 2);
    bf16_t* wkvwT  = (bf16_t*)alloc((size_t)5120 * RDIM * 2);
    bf16_t* wqT    = (bf16_t*)alloc((size_t)3072 * DMODEL * 2);
    bf16_t* woT    = (bf16_t*)alloc((size_t)DMODEL * DMODEL * 2);
    float*  kvf    = (float*) alloc((size_t)MROWS * RDIM * 4);
    bf16_t* kvb    = (bf16_t*)alloc((size_t)MROWS * RDIM * 2);
    bf16_t* kvout  = (bf16_t*)alloc((size_t)MROWS * 5120 * 2);
    bf16_t* qfull  = (bf16_t*)alloc((size_t)MROWS * 3072 * 2);
    bf16_t* vt     = (bf16_t*)alloc((size_t)32 * 128 * SEQ * 2);
    bf16_t* attno  = (bf16_t*)alloc((size_t)MROWS * 2048 * 2);
    float*  costab = (float*) alloc((size_t)SEQ * 32 * 4);
    float*  sintab = (float*) alloc((size_t)SEQ * 32 * 4);

    // prep
    cast_x_kernel<<<(MROWS * DMODEL / 4) / 256, 256, 0, stream>>>(x, xb);
    wtrans_kernel<<<dim3(RDIM / 32, DMODEL / 32), 256, 0, stream>>>(w_kv, wkvT, DMODEL, RDIM);
    wtrans_kernel<<<dim3(3072 / 32, RDIM / 32), 256, 0, stream>>>(w_k, wkvwT, RDIM, 3072);
    wtrans_kernel<<<dim3(2048 / 32, RDIM / 32), 256, 0, stream>>>(w_v, wkvwT + (size_t)3072 * RDIM, RDIM, 2048);
    wtrans_kernel<<<dim3(2048 / 32, DMODEL / 32), 256, 0, stream>>>(w_qn, wqT, DMODEL, 2048);
    wtrans_kernel<<<dim3(1024 / 32, DMODEL / 32), 256, 0, stream>>>(w_qr, wqT + (size_t)2048 * DMODEL, DMODEL, 1024);
    wtrans_kernel<<<dim3(2048 / 32, DMODEL / 32), 256, 0, stream>>>(w_o, woT, DMODEL, 2048);
    rope_table_kernel<<<(SEQ * 32) / 256, 256, 0, stream>>>(freqs, costab, sintab);

    // G1: kv_pre = x @ w_kv   (f32 out for rmsnorm)
    gemm_bt<float, 0><<<dim3(RDIM / 128, MROWS / 128), 256, 0, stream>>>(xb, wkvT, kvf, MROWS, RDIM, DMODEL, nullptr, nullptr);
    rmsnorm_kernel<<<MROWS, 256, 0, stream>>>(kvf, g_kv, kvb);
    // G2: [k_full | v] = kv @ [w_k | w_v], rope fused on k-rope cols
    gemm_bt<bf16_t, 1><<<dim3(5120 / 128, MROWS / 128), 256, 0, stream>>>(kvb, wkvwT, kvout, MROWS, 5120, RDIM, costab, sintab);
    // G3: [q_nope | q_rope] = x @ [w_qn | w_qr], rope fused on cols >= 2048
    gemm_bt<bf16_t, 2><<<dim3(3072 / 128, MROWS / 128), 256, 0, stream>>>(xb, wqT, qfull, MROWS, 3072, DMODEL, costab, sintab);

    // v transpose only (k/q consumed in native layouts)
    pack_v_kernel<<<32 * 32, 256, 0, stream>>>(kvout, vt);

    // attention (512 blocks x 8 waves: 32 bh x 16 q-tiles of 128 rows)
    attn_kernel<<<512, 512, 0, stream>>>(qfull, kvout, vt, attno);

    // G4: out = attn_out @ w_o   (f32 out)
    gemm_bt<float, 0><<<dim3(2048 / 128, MROWS / 128), 256, 0, stream>>>(attno, woT, out, MROWS, 2048, DMODEL, nullptr, nullptr);
}

// Round 9
// 351.138 us; speedup vs baseline: 1.2422x; 1.2422x over previous
//
#include <hip/hip_runtime.h>

typedef __bf16 bf16_t;
typedef bf16_t bf16x8 __attribute__((ext_vector_type(8)));
typedef bf16_t bf16x4v __attribute__((ext_vector_type(4)));
typedef float f32x4 __attribute__((ext_vector_type(4)));

#define GLDS16(g, l) __builtin_amdgcn_global_load_lds( \
    (const __attribute__((address_space(1))) void*)(g), \
    (__attribute__((address_space(3))) void*)(l), 16, 0, 0)

// Problem constants
#define BB 2
#define SEQ 2048
#define DMODEL 2048
#define RDIM 512
#define NH 16
#define DNOPE 128
#define DROPE 64
#define DVDIM 128
#define MROWS 4096           // BB*SEQ
#define DQK 192              // DNOPE+DROPE

// ---------------- prep kernels ----------------

__global__ __launch_bounds__(256) void cast_x_kernel(const float* __restrict__ x,
                                                     bf16_t* __restrict__ xb) {
    int idx = blockIdx.x * 256 + threadIdx.x;
    float4 v = ((const float4*)x)[idx];
    bf16x4v o;
    o[0] = (bf16_t)v.x; o[1] = (bf16_t)v.y; o[2] = (bf16_t)v.z; o[3] = (bf16_t)v.w;
    ((bf16x4v*)xb)[idx] = o;
}

// W (K x N) f32 -> WT (N x K) bf16, tiled transpose
__global__ __launch_bounds__(256) void wtrans_kernel(const float* __restrict__ W,
                                                     bf16_t* __restrict__ WT,
                                                     int K, int N) {
    __shared__ float t[32][33];
    int n0 = blockIdx.x * 32, k0 = blockIdx.y * 32;
    int tx = threadIdx.x & 31, ty = threadIdx.x >> 5;  // ty 0..7
    #pragma unroll
    for (int i = 0; i < 4; ++i)
        t[ty + i*8][tx] = W[(size_t)(k0 + ty + i*8) * N + n0 + tx];
    __syncthreads();
    #pragma unroll
    for (int i = 0; i < 4; ++i)
        WT[(size_t)(n0 + ty + i*8) * K + k0 + tx] = (bf16_t)t[tx][ty + i*8];
}

__global__ __launch_bounds__(256) void rope_table_kernel(const float* __restrict__ freqs,
                                                         float* __restrict__ costab,
                                                         float* __restrict__ sintab) {
    int idx = blockIdx.x * 256 + threadIdx.x;   // SEQ*32 exact
    float f = freqs[idx];
    costab[idx] = cosf(f);
    sintab[idx] = sinf(f);
}

__global__ __launch_bounds__(256) void rmsnorm_kernel(const float* __restrict__ kvf,
                                                      const float* __restrict__ gkv,
                                                      bf16_t* __restrict__ kvb) {
    int m = blockIdx.x;
    int tid = threadIdx.x;
    const float* rowp = kvf + (size_t)m * RDIM;
    float2 v = *(const float2*)(rowp + tid * 2);
    float ss = v.x * v.x + v.y * v.y;
    #pragma unroll
    for (int d = 1; d < 64; d <<= 1) ss += __shfl_xor(ss, d, 64);
    __shared__ float red[4];
    if ((tid & 63) == 0) red[tid >> 6] = ss;
    __syncthreads();
    float tot = red[0] + red[1] + red[2] + red[3];
    float scale = rsqrtf(tot * (1.0f / RDIM) + 1e-6f);
    bf16_t* orow = kvb + (size_t)m * RDIM;
    orow[tid*2]     = (bf16_t)(v.x * scale * gkv[tid*2]);
    orow[tid*2 + 1] = (bf16_t)(v.y * scale * gkv[tid*2 + 1]);
}

// ---------------- GEMM: C(MxN) = A(MxK) * Bt(NxK)^T, bf16 in, OutT out --------
// 128x128 tile, BK=64, 4 waves (2x2), global_load_lds staging with XOR swizzle.
// EPI: 0 = plain store; 1 = kvout (rope cols n<3072 with n%192>=128);
//      2 = qfull (rope cols n>=2048). Rope pairs live in lanes (c, c^1).

template<typename OutT, int EPI>
__global__ __launch_bounds__(256, 2) void gemm_bt(const bf16_t* __restrict__ A,
                                                  const bf16_t* __restrict__ Bt,
                                                  OutT* __restrict__ C,
                                                  int M, int N, int K,
                                                  const float* __restrict__ costab,
                                                  const float* __restrict__ sintab) {
    __shared__ __align__(16) char ldsA[128 * 128];   // 128 rows x 128B (64 bf16)
    __shared__ __align__(16) char ldsB[128 * 128];
    int tid = threadIdx.x;
    int lane = tid & 63, wave = tid >> 6;
    int n0 = blockIdx.x * 128, m0 = blockIdx.y * 128;
    int wr = wave >> 1, wc = wave & 1;
    int g = lane >> 4, c = lane & 15;
    f32x4 acc[4][4] = {};

    int srow = tid >> 3;         // 0..31: row within 4KB staging slab
    int sch = tid & 7;           // chunk (16B) within 128B row

    int nkt = K >> 6;
    for (int kt = 0; kt < nkt; ++kt) {
        int k0 = kt << 6;
        #pragma unroll
        for (int j = 0; j < 4; ++j) {
            int row = j * 32 + srow;
            int csrc = sch ^ (row & 7);     // pre-swizzled source chunk
            const char* gA = (const char*)(A + (size_t)(m0 + row) * K + k0) + csrc * 16;
            const char* gB = (const char*)(Bt + (size_t)(n0 + row) * K + k0) + csrc * 16;
            char* lA = ldsA + j * 4096 + wave * 1024;
            char* lB = ldsB + j * 4096 + wave * 1024;
            GLDS16(gA, lA);
            GLDS16(gB, lB);
        }
        __syncthreads();
        #pragma unroll
        for (int kk = 0; kk < 2; ++kk) {
            int kb = kk * 64 + g * 16;      // byte offset within row
            bf16x8 aF[4], bF[4];
            #pragma unroll
            for (int m = 0; m < 4; ++m) {
                int row = wr * 64 + m * 16 + c;
                aF[m] = *(const bf16x8*)(ldsA + row * 128 + (kb ^ ((row & 7) << 4)));
            }
            #pragma unroll
            for (int n = 0; n < 4; ++n) {
                int row = wc * 64 + n * 16 + c;
                bF[n] = *(const bf16x8*)(ldsB + row * 128 + (kb ^ ((row & 7) << 4)));
            }
            #pragma unroll
            for (int m = 0; m < 4; ++m)
                #pragma unroll
                for (int n = 0; n < 4; ++n)
                    acc[m][n] = __builtin_amdgcn_mfma_f32_16x16x32_bf16(aF[m], bF[n], acc[m][n], 0, 0, 0);
        }
        __syncthreads();
    }
    // epilogue: C/D layout col=lane&15, row=(lane>>4)*4+i
    #pragma unroll
    for (int m = 0; m < 4; ++m) {
        int grow0 = m0 + wr * 64 + m * 16 + g * 4;
        #pragma unroll
        for (int n = 0; n < 4; ++n) {
            int gcol = n0 + wc * 64 + n * 16 + c;
            bool rope = false;
            int j = 0;
            if (EPI == 1) {
                rope = (gcol < 3072) && ((gcol % 192) >= 128);
                j = ((gcol % 192) - 128) >> 1;
            } else if (EPI == 2) {
                rope = (gcol >= 2048);
                j = ((gcol - 2048) & 63) >> 1;
            }
            if (EPI != 0 && rope) {
                bool even = (c & 1) == 0;
                #pragma unroll
                for (int i = 0; i < 4; ++i) {
                    float v = acc[m][n][i];
                    float pv = __shfl_xor(v, 1, 64);
                    int s = (grow0 + i) & (SEQ - 1);
                    float cs = costab[s * 32 + j], sn = sintab[s * 32 + j];
                    float o = even ? (v * cs - pv * sn) : (pv * sn + v * cs);
                    C[(size_t)(grow0 + i) * N + gcol] = (OutT)o;
                }
            } else {
                #pragma unroll
                for (int i = 0; i < 4; ++i)
                    C[(size_t)(grow0 + i) * N + gcol] = (OutT)acc[m][n][i];
            }
        }
    }
}

// v part of kvout -> vt [BH][128][SEQ]  (transposed for PV B-fragments)
__global__ __launch_bounds__(256) void pack_v_kernel(const bf16_t* __restrict__ kvout,
                                                     bf16_t* __restrict__ vt) {
    __shared__ bf16_t t[64][144];
    int blk = blockIdx.x;                 // 32 bh * 32 stiles
    int bh = blk >> 5, st = blk & 31;
    int s0 = st * 64;
    int b = bh >> 4, h = bh & 15;
    int tid = threadIdx.x;
    #pragma unroll
    for (int i = 0; i < 4; ++i) {
        int id = i * 256 + tid;           // 1024: 64 rows x 16 chunks
        int row = id >> 4, ch = id & 15;
        bf16x8 v = *(const bf16x8*)(kvout + (size_t)(b * SEQ + s0 + row) * 5120 + 3072 + h * 128 + ch * 8);
        *(bf16x8*)&t[row][ch * 8] = v;
    }
    __syncthreads();
    #pragma unroll
    for (int i = 0; i < 4; ++i) {
        int id = i * 256 + tid;           // 1024: 128 dv x 8 chunks
        int dv = id >> 3, sc = id & 7;
        bf16x8 v;
        #pragma unroll
        for (int jj = 0; jj < 8; ++jj) v[jj] = t[sc * 8 + jj][dv];
        *(bf16x8*)(vt + ((size_t)bh * 128 + dv) * SEQ + s0 + sc * 8) = v;
    }
}

// ---------------- flash attention v6b ----------------
// Q direct from qfull [M][3072]; K direct from kvout [M][5120] (h*192 slice);
// VT: [BH][128][S]; O: [M][2048] (col=h*128+dv).
// 512 blocks x 512 threads (8 waves). Each block: 128 q-rows; wave w owns rows
// q0+w*16..+15. KV tile 64 staged once per tile for all 8 waves. 2 blocks/CU,
// all resident; heavy/light pairing keeps per-CU work constant (36 tiles).
// Ones-column row-sum; defer-max (THR=8).
// NOTE launch_bounds (512,2): R8's (512,4) was interpreted as 4 blocks/CU ->
// 64-VGPR cap -> 515 MB scratch spill. (512,2) caps at >=128 VGPR.

__global__ __launch_bounds__(512, 2) void attn_kernel(const bf16_t* __restrict__ Qf,
                                                      const bf16_t* __restrict__ KV,
                                                      const bf16_t* __restrict__ VT,
                                                      bf16_t* __restrict__ O) {
    __shared__ __align__(16) char ldsK[64 * 384];     // [64][192] bf16, swizzled content
    __shared__ __align__(16) char ldsV[128 * 128];    // [128 dv][64 s] bf16, swizzled content
    __shared__ __align__(16) char ldsP[8 * 16 * 176]; // per-wave [16][64+24pad] bf16
    int tid = threadIdx.x, lane = tid & 63, wave = tid >> 6;   // wave 0..7
    int g = lane >> 4, c = lane & 15;

    // XCD-aware mapping; slot<8 -> heavy (qt=15-slot), else light (qt=slot-8):
    // pair (bid, bid+256) sums to 36 tiles -> constant per-CU work.
    int bid = blockIdx.x;                // 0..511
    int xcd = bid & 7, rest = bid >> 3;  // rest 0..63
    int bh = xcd * 4 + (rest & 3);       // 0..31
    int slot = rest >> 2;                // 0..15
    int qt = (slot < 8) ? (15 - slot) : (slot - 8);
    int b = bh >> 4, h = bh & 15;
    int q0 = qt * 128;
    int nt = 2 * qt + 2;
    int tdiag = 2 * qt + (wave >> 2);    // this wave's diagonal tile

    const bf16_t* Kb = KV + (size_t)b * SEQ * 5120 + h * DQK;   // + s*5120
    const bf16_t* Vb = VT + (size_t)bh * 128 * SEQ;
    char* ldsPw = ldsP + wave * (16 * 176);

    // K staging map: 1536 chunks of 16B over 512 threads (3 issues);
    // source chunk XORed so linear LDS + swizzled read composes to identity.
    size_t soff[3];
    #pragma unroll
    for (int i2 = 0; i2 < 3; ++i2) {
        int id = i2 * 512 + tid;
        int row = id / 24, ch = id - row * 24;
        soff[i2] = (size_t)row * 10240 + (ch ^ (row & 7)) * 16;
    }
    // V staging map: 1024 chunks over 512 threads (2 issues).
    size_t voff[2];
    #pragma unroll
    for (int i2 = 0; i2 < 2; ++i2) {
        int id = i2 * 512 + tid;
        int row = id >> 3, ch = id & 7;
        voff[i2] = (size_t)row * (SEQ * 2) + (ch ^ (row & 7)) * 16;
    }
    const float sc = 0.0721687836f * 1.44269504f;   // 1/sqrt(192) * log2(e)

    bf16x8 vones;
    #pragma unroll
    for (int j = 0; j < 8; ++j) vones[j] = (bf16_t)1.0f;

    // Q fragments: lane (g,c) holds Q[row = q0+wave*16+c][k = kk*32 + g*8 + 0..7]
    bf16x8 qf[6];
    {
        int qrow = q0 + wave * 16 + c;
        const bf16_t* qn = Qf + (size_t)(b * SEQ + qrow) * 3072 + h * DNOPE + g * 8;
        #pragma unroll
        for (int kk = 0; kk < 4; ++kk) qf[kk] = *(const bf16x8*)(qn + kk * 32);
        const bf16_t* qr = Qf + (size_t)(b * SEQ + qrow) * 3072 + 2048 + h * DROPE + g * 8;
        qf[4] = *(const bf16x8*)(qr);
        qf[5] = *(const bf16x8*)(qr + 32);
    }
    float m_run[4];
    f32x4 accO[9] = {};                        // [8] = running row-sum (ones column)
    #pragma unroll
    for (int i = 0; i < 4; ++i) m_run[i] = -3.0e38f;

    #pragma unroll 1
    for (int t = 0; t < nt; ++t) {
        // stage K tile (24KB) + V tile (16KB) via global_load_lds (all 8 waves)
        const char* Kt = (const char*)(Kb + (size_t)t * 64 * 5120);
        #pragma unroll
        for (int i2 = 0; i2 < 3; ++i2)
            GLDS16(Kt + soff[i2], ldsK + i2 * 8192 + wave * 1024);
        const char* Vt = (const char*)Vb + (size_t)t * 128;   // t*64 elems
        #pragma unroll
        for (int i2 = 0; i2 < 2; ++i2)
            GLDS16(Vt + voff[i2], ldsV + i2 * 8192 + wave * 1024);
        __syncthreads();

        if (t <= tdiag) {                      // wave-uniform; no barrier inside
            bool diag = (t == tdiag);

            // QK^T: 16 q-rows x 64 k
            f32x4 accS[4] = {};
            __builtin_amdgcn_s_setprio(1);
            #pragma unroll
            for (int kk = 0; kk < 6; ++kk) {
                int kb = kk * 64 + g * 16;
                #pragma unroll
                for (int n = 0; n < 4; ++n) {
                    int row = n * 16 + c;
                    bf16x8 kf = *(const bf16x8*)(ldsK + row * 384 + (kb ^ ((row & 7) << 4)));
                    accS[n] = __builtin_amdgcn_mfma_f32_16x16x32_bf16(qf[kk], kf, accS[n], 0, 0, 0);
                }
            }
            __builtin_amdgcn_s_setprio(0);

            // scale + causal mask (diag tile: in-tile row offset = (wave&3)*16)
            #pragma unroll
            for (int n = 0; n < 4; ++n)
                #pragma unroll
                for (int i = 0; i < 4; ++i) {
                    float v = accS[n][i] * sc;
                    if (diag && (n * 16 + c > (wave & 3) * 16 + g * 4 + i)) v = -1e30f;
                    accS[n][i] = v;
                }
            // row max; sum comes free via ones-column MFMA
            float mx[4];
            #pragma unroll
            for (int i = 0; i < 4; ++i) {
                float m2 = fmaxf(fmaxf(accS[0][i], accS[1][i]), fmaxf(accS[2][i], accS[3][i]));
                #pragma unroll
                for (int d = 1; d < 16; d <<= 1) m2 = fmaxf(m2, __shfl_xor(m2, d, 64));
                mx[i] = m2;
            }
            bool nore = __all((mx[0] <= m_run[0] + 8.f) & (mx[1] <= m_run[1] + 8.f) &
                              (mx[2] <= m_run[2] + 8.f) & (mx[3] <= m_run[3] + 8.f));
            if (nore) {
                #pragma unroll
                for (int i = 0; i < 4; ++i)
                    #pragma unroll
                    for (int n = 0; n < 4; ++n)
                        accS[n][i] = exp2f(accS[n][i] - m_run[i]);
            } else {
                #pragma unroll
                for (int i = 0; i < 4; ++i) {
                    float mnew = fmaxf(m_run[i], mx[i]);
                    float alpha = exp2f(m_run[i] - mnew);
                    m_run[i] = mnew;
                    #pragma unroll
                    for (int n = 0; n < 4; ++n)
                        accS[n][i] = exp2f(accS[n][i] - mnew);
                    #pragma unroll
                    for (int n = 0; n < 9; ++n) accO[n][i] *= alpha;
                }
            }
            // P (C-frag) -> per-wave LDS -> A-frag
            #pragma unroll
            for (int n = 0; n < 4; ++n)
                #pragma unroll
                for (int i = 0; i < 4; ++i)
                    *(bf16_t*)(ldsPw + (g * 4 + i) * 176 + (n * 16 + c) * 2) = (bf16_t)accS[n][i];
            bf16x8 pf0 = *(const bf16x8*)(ldsPw + c * 176 + g * 16);
            bf16x8 pf1 = *(const bf16x8*)(ldsPw + c * 176 + 64 + g * 16);

            // PV: V from LDS (swizzled read), plus ones-column for row-sum
            __builtin_amdgcn_s_setprio(1);
            #pragma unroll
            for (int n = 0; n < 8; ++n) {
                int row = n * 16 + c;
                bf16x8 vf0 = *(const bf16x8*)(ldsV + row * 128 + ((g * 16) ^ ((c & 7) << 4)));
                bf16x8 vf1 = *(const bf16x8*)(ldsV + row * 128 + ((64 + g * 16) ^ ((c & 7) << 4)));
                accO[n] = __builtin_amdgcn_mfma_f32_16x16x32_bf16(pf0, vf0, accO[n], 0, 0, 0);
                accO[n] = __builtin_amdgcn_mfma_f32_16x16x32_bf16(pf1, vf1, accO[n], 0, 0, 0);
            }
            accO[8] = __builtin_amdgcn_mfma_f32_16x16x32_bf16(pf0, vones, accO[8], 0, 0, 0);
            accO[8] = __builtin_amdgcn_mfma_f32_16x16x32_bf16(pf1, vones, accO[8], 0, 0, 0);
            __builtin_amdgcn_s_setprio(0);
        }
        __syncthreads();   // all waves done with ldsK/ldsV before next stage
    }
    // write O, normalizing by the ones-column running sum
    float inv_l[4];
    #pragma unroll
    for (int i = 0; i < 4; ++i) inv_l[i] = 1.0f / accO[8][i];
    #pragma unroll
    for (int n = 0; n < 8; ++n) {
        int gcol = h * 128 + n * 16 + c;
        #pragma unroll
        for (int i = 0; i < 4; ++i) {
            int mrow = b * SEQ + q0 + wave * 16 + g * 4 + i;
            O[(size_t)mrow * 2048 + gcol] = (bf16_t)(accO[n][i] * inv_l[i]);
        }
    }
}

// ---------------- launch ----------------

extern "C" void kernel_launch(void* const* d_in, const int* in_sizes, int n_in,
                              void* d_out, int out_size, void* d_ws, size_t ws_size,
                              hipStream_t stream) {
    const float* x     = (const float*)d_in[0];
    const float* freqs = (const float*)d_in[1];
    const float* w_kv  = (const float*)d_in[2];
    const float* g_kv  = (const float*)d_in[3];
    const float* w_k   = (const float*)d_in[4];
    const float* w_v   = (const float*)d_in[5];
    const float* w_qn  = (const float*)d_in[6];
    const float* w_qr  = (const float*)d_in[7];
    const float* w_o   = (const float*)d_in[8];
    float* out = (float*)d_out;

    char* ws = (char*)d_ws;
    size_t off = 0;
    auto alloc = [&](size_t bytes) { char* p = ws + off; off += (bytes + 255) & ~(size_t)255; return p; };
    bf16_t* xb     = (bf16_t*)alloc((size_t)MROWS * DMODEL * 2);
    bf16_t* wkvT   = (bf16_t*)alloc((size_t)RDIM * DMODEL * 2);
    bf16_t* wkvwT  = (bf16_t*)alloc((size_t)5120 * RDIM * 2);
    bf16_t* wqT    = (bf16_t*)alloc((size_t)3072 * DMODEL * 2);
    bf16_t* woT    = (bf16_t*)alloc((size_t)DMODEL * DMODEL * 2);
    float*  kvf    = (float*) alloc((size_t)MROWS * RDIM * 4);
    bf16_t* kvb    = (bf16_t*)alloc((size_t)MROWS * RDIM * 2);
    bf16_t* kvout  = (bf16_t*)alloc((size_t)MROWS * 5120 * 2);
    bf16_t* qfull  = (bf16_t*)alloc((size_t)MROWS * 3072 * 2);
    bf16_t* vt     = (bf16_t*)alloc((size_t)32 * 128 * SEQ * 2);
    bf16_t* attno  = (bf16_t*)alloc((size_t)MROWS * 2048 * 2);
    float*  costab = (float*) alloc((size_t)SEQ * 32 * 4);
    float*  sintab = (float*) alloc((size_t)SEQ * 32 * 4);

    // prep
    cast_x_kernel<<<(MROWS * DMODEL / 4) / 256, 256, 0, stream>>>(x, xb);
    wtrans_kernel<<<dim3(RDIM / 32, DMODEL / 32), 256, 0, stream>>>(w_kv, wkvT, DMODEL, RDIM);
    wtrans_kernel<<<dim3(3072 / 32, RDIM / 32), 256, 0, stream>>>(w_k, wkvwT, RDIM, 3072);
    wtrans_kernel<<<dim3(2048 / 32, RDIM / 32), 256, 0, stream>>>(w_v, wkvwT + (size_t)3072 * RDIM, RDIM, 2048);
    wtrans_kernel<<<dim3(2048 / 32, DMODEL / 32), 256, 0, stream>>>(w_qn, wqT, DMODEL, 2048);
    wtrans_kernel<<<dim3(1024 / 32, DMODEL / 32), 256, 0, stream>>>(w_qr, wqT + (size_t)2048 * DMODEL, DMODEL, 1024);
    wtrans_kernel<<<dim3(2048 / 32, DMODEL / 32), 256, 0, stream>>>(w_o, woT, DMODEL, 2048);
    rope_table_kernel<<<(SEQ * 32) / 256, 256, 0, stream>>>(freqs, costab, sintab);

    // G1: kv_pre = x @ w_kv   (f32 out for rmsnorm)
    gemm_bt<float, 0><<<dim3(RDIM / 128, MROWS / 128), 256, 0, stream>>>(xb, wkvT, kvf, MROWS, RDIM, DMODEL, nullptr, nullptr);
    rmsnorm_kernel<<<MROWS, 256, 0, stream>>>(kvf, g_kv, kvb);
    // G2: [k_full | v] = kv @ [w_k | w_v], rope fused on k-rope cols
    gemm_bt<bf16_t, 1><<<dim3(5120 / 128, MROWS / 128), 256, 0, stream>>>(kvb, wkvwT, kvout, MROWS, 5120, RDIM, costab, sintab);
    // G3: [q_nope | q_rope] = x @ [w_qn | w_qr], rope fused on cols >= 2048
    gemm_bt<bf16_t, 2><<<dim3(3072 / 128, MROWS / 128), 256, 0, stream>>>(xb, wqT, qfull, MROWS, 3072, DMODEL, costab, sintab);

    // v transpose only (k/q consumed in native layouts)
    pack_v_kernel<<<32 * 32, 256, 0, stream>>>(kvout, vt);

    // attention (512 blocks x 8 waves: 32 bh x 16 q-tiles of 128 rows)
    attn_kernel<<<512, 512, 0, stream>>>(qfull, kvout, vt, attno);

    // G4: out = attn_out @ w_o   (f32 out)
    gemm_bt<float, 0><<<dim3(2048 / 128, MROWS / 128), 256, 0, stream>>>(attno, woT, out, MROWS, 2048, DMODEL, nullptr, nullptr);
}

// Round 10
// 324.167 us; speedup vs baseline: 1.3455x; 1.0832x over previous
//
#include <hip/hip_runtime.h>

typedef __bf16 bf16_t;
typedef bf16_t bf16x8 __attribute__((ext_vector_type(8)));
typedef bf16_t bf16x4v __attribute__((ext_vector_type(4)));
typedef float f32x4 __attribute__((ext_vector_type(4)));

#define GLDS16(g, l) __builtin_amdgcn_global_load_lds( \
    (const __attribute__((address_space(1))) void*)(g), \
    (__attribute__((address_space(3))) void*)(l), 16, 0, 0)

// Problem constants
#define BB 2
#define SEQ 2048
#define DMODEL 2048
#define RDIM 512
#define NH 16
#define DNOPE 128
#define DROPE 64
#define DVDIM 128
#define MROWS 4096           // BB*SEQ
#define DQK 192              // DNOPE+DROPE

// ---------------- prep kernels ----------------

__global__ __launch_bounds__(256) void cast_x_kernel(const float* __restrict__ x,
                                                     bf16_t* __restrict__ xb) {
    int idx = blockIdx.x * 256 + threadIdx.x;
    float4 v = ((const float4*)x)[idx];
    bf16x4v o;
    o[0] = (bf16_t)v.x; o[1] = (bf16_t)v.y; o[2] = (bf16_t)v.z; o[3] = (bf16_t)v.w;
    ((bf16x4v*)xb)[idx] = o;
}

// W (K x N) f32 -> WT (N x K) bf16, tiled transpose
__global__ __launch_bounds__(256) void wtrans_kernel(const float* __restrict__ W,
                                                     bf16_t* __restrict__ WT,
                                                     int K, int N) {
    __shared__ float t[32][33];
    int n0 = blockIdx.x * 32, k0 = blockIdx.y * 32;
    int tx = threadIdx.x & 31, ty = threadIdx.x >> 5;  // ty 0..7
    #pragma unroll
    for (int i = 0; i < 4; ++i)
        t[ty + i*8][tx] = W[(size_t)(k0 + ty + i*8) * N + n0 + tx];
    __syncthreads();
    #pragma unroll
    for (int i = 0; i < 4; ++i)
        WT[(size_t)(n0 + ty + i*8) * K + k0 + tx] = (bf16_t)t[tx][ty + i*8];
}

__global__ __launch_bounds__(256) void rope_table_kernel(const float* __restrict__ freqs,
                                                         float* __restrict__ costab,
                                                         float* __restrict__ sintab) {
    int idx = blockIdx.x * 256 + threadIdx.x;   // SEQ*32 exact
    float f = freqs[idx];
    costab[idx] = cosf(f);
    sintab[idx] = sinf(f);
}

__global__ __launch_bounds__(256) void rmsnorm_kernel(const float* __restrict__ kvf,
                                                      const float* __restrict__ gkv,
                                                      bf16_t* __restrict__ kvb) {
    int m = blockIdx.x;
    int tid = threadIdx.x;
    const float* rowp = kvf + (size_t)m * RDIM;
    float2 v = *(const float2*)(rowp + tid * 2);
    float ss = v.x * v.x + v.y * v.y;
    #pragma unroll
    for (int d = 1; d < 64; d <<= 1) ss += __shfl_xor(ss, d, 64);
    __shared__ float red[4];
    if ((tid & 63) == 0) red[tid >> 6] = ss;
    __syncthreads();
    float tot = red[0] + red[1] + red[2] + red[3];
    float scale = rsqrtf(tot * (1.0f / RDIM) + 1e-6f);
    bf16_t* orow = kvb + (size_t)m * RDIM;
    orow[tid*2]     = (bf16_t)(v.x * scale * gkv[tid*2]);
    orow[tid*2 + 1] = (bf16_t)(v.y * scale * gkv[tid*2 + 1]);
}

// ---------------- GEMM: C(MxN) = A(MxK) * Bt(NxK)^T, bf16 in, OutT out --------
// 128x128 tile, BK=64, 4 waves (2x2), global_load_lds staging with XOR swizzle.
// EPI: 0 = plain store; 1 = kvout (rope cols n<3072 with n%192>=128);
//      2 = qfull (rope cols n>=2048). Rope pairs live in lanes (c, c^1).

template<typename OutT, int EPI>
__global__ __launch_bounds__(256, 2) void gemm_bt(const bf16_t* __restrict__ A,
                                                  const bf16_t* __restrict__ Bt,
                                                  OutT* __restrict__ C,
                                                  int M, int N, int K,
                                                  const float* __restrict__ costab,
                                                  const float* __restrict__ sintab) {
    __shared__ __align__(16) char ldsA[128 * 128];   // 128 rows x 128B (64 bf16)
    __shared__ __align__(16) char ldsB[128 * 128];
    int tid = threadIdx.x;
    int lane = tid & 63, wave = tid >> 6;
    int n0 = blockIdx.x * 128, m0 = blockIdx.y * 128;
    int wr = wave >> 1, wc = wave & 1;
    int g = lane >> 4, c = lane & 15;
    f32x4 acc[4][4] = {};

    int srow = tid >> 3;         // 0..31: row within 4KB staging slab
    int sch = tid & 7;           // chunk (16B) within 128B row

    int nkt = K >> 6;
    for (int kt = 0; kt < nkt; ++kt) {
        int k0 = kt << 6;
        #pragma unroll
        for (int j = 0; j < 4; ++j) {
            int row = j * 32 + srow;
            int csrc = sch ^ (row & 7);     // pre-swizzled source chunk
            const char* gA = (const char*)(A + (size_t)(m0 + row) * K + k0) + csrc * 16;
            const char* gB = (const char*)(Bt + (size_t)(n0 + row) * K + k0) + csrc * 16;
            char* lA = ldsA + j * 4096 + wave * 1024;
            char* lB = ldsB + j * 4096 + wave * 1024;
            GLDS16(gA, lA);
            GLDS16(gB, lB);
        }
        __syncthreads();
        #pragma unroll
        for (int kk = 0; kk < 2; ++kk) {
            int kb = kk * 64 + g * 16;      // byte offset within row
            bf16x8 aF[4], bF[4];
            #pragma unroll
            for (int m = 0; m < 4; ++m) {
                int row = wr * 64 + m * 16 + c;
                aF[m] = *(const bf16x8*)(ldsA + row * 128 + (kb ^ ((row & 7) << 4)));
            }
            #pragma unroll
            for (int n = 0; n < 4; ++n) {
                int row = wc * 64 + n * 16 + c;
                bF[n] = *(const bf16x8*)(ldsB + row * 128 + (kb ^ ((row & 7) << 4)));
            }
            #pragma unroll
            for (int m = 0; m < 4; ++m)
                #pragma unroll
                for (int n = 0; n < 4; ++n)
                    acc[m][n] = __builtin_amdgcn_mfma_f32_16x16x32_bf16(aF[m], bF[n], acc[m][n], 0, 0, 0);
        }
        __syncthreads();
    }
    // epilogue: C/D layout col=lane&15, row=(lane>>4)*4+i
    #pragma unroll
    for (int m = 0; m < 4; ++m) {
        int grow0 = m0 + wr * 64 + m * 16 + g * 4;
        #pragma unroll
        for (int n = 0; n < 4; ++n) {
            int gcol = n0 + wc * 64 + n * 16 + c;
            bool rope = false;
            int j = 0;
            if (EPI == 1) {
                rope = (gcol < 3072) && ((gcol % 192) >= 128);
                j = ((gcol % 192) - 128) >> 1;
            } else if (EPI == 2) {
                rope = (gcol >= 2048);
                j = ((gcol - 2048) & 63) >> 1;
            }
            if (EPI != 0 && rope) {
                bool even = (c & 1) == 0;
                #pragma unroll
                for (int i = 0; i < 4; ++i) {
                    float v = acc[m][n][i];
                    float pv = __shfl_xor(v, 1, 64);
                    int s = (grow0 + i) & (SEQ - 1);
                    float cs = costab[s * 32 + j], sn = sintab[s * 32 + j];
                    float o = even ? (v * cs - pv * sn) : (pv * sn + v * cs);
                    C[(size_t)(grow0 + i) * N + gcol] = (OutT)o;
                }
            } else {
                #pragma unroll
                for (int i = 0; i < 4; ++i)
                    C[(size_t)(grow0 + i) * N + gcol] = (OutT)acc[m][n][i];
            }
        }
    }
}

// v part of kvout -> vt [BH][128][SEQ]  (transposed for PV B-fragments)
__global__ __launch_bounds__(256) void pack_v_kernel(const bf16_t* __restrict__ kvout,
                                                     bf16_t* __restrict__ vt) {
    __shared__ bf16_t t[64][144];
    int blk = blockIdx.x;                 // 32 bh * 32 stiles
    int bh = blk >> 5, st = blk & 31;
    int s0 = st * 64;
    int b = bh >> 4, h = bh & 15;
    int tid = threadIdx.x;
    #pragma unroll
    for (int i = 0; i < 4; ++i) {
        int id = i * 256 + tid;           // 1024: 64 rows x 16 chunks
        int row = id >> 4, ch = id & 15;
        bf16x8 v = *(const bf16x8*)(kvout + (size_t)(b * SEQ + s0 + row) * 5120 + 3072 + h * 128 + ch * 8);
        *(bf16x8*)&t[row][ch * 8] = v;
    }
    __syncthreads();
    #pragma unroll
    for (int i = 0; i < 4; ++i) {
        int id = i * 256 + tid;           // 1024: 128 dv x 8 chunks
        int dv = id >> 3, sc = id & 7;
        bf16x8 v;
        #pragma unroll
        for (int jj = 0; jj < 8; ++jj) v[jj] = t[sc * 8 + jj][dv];
        *(bf16x8*)(vt + ((size_t)bh * 128 + dv) * SEQ + s0 + sc * 8) = v;
    }
}

// ---------------- flash attention v7 ----------------
// Q direct from qfull [M][3072]; K direct from kvout [M][5120] (h*192 slice);
// VT: [BH][128][S]; O: [M][2048] (col=h*128+dv).
// 256 blocks (1/CU) x 512 threads (8 waves). Each block: TWO 128-row q-tiles
// (heavy qt=15-p, then light qt=p) -> exactly 36 KV tiles per CU, perfect
// balance. K/V DOUBLE-BUFFERED: stage(t+1) issued before compute(t), single
// __syncthreads per tile (its vmcnt(0) drain lands after compute hides the
// latency). Ones-column row-sum; defer-max (THR=8).

__global__ __launch_bounds__(512, 2) void attn_kernel(const bf16_t* __restrict__ Qf,
                                                      const bf16_t* __restrict__ KV,
                                                      const bf16_t* __restrict__ VT,
                                                      bf16_t* __restrict__ O) {
    __shared__ __align__(16) char ldsK[2 * 64 * 384];   // dbuf [64][192] bf16, swizzled content
    __shared__ __align__(16) char ldsV[2 * 128 * 128];  // dbuf [128 dv][64 s] bf16, swizzled content
    __shared__ __align__(16) char ldsP[8 * 16 * 176];   // per-wave [16][64+24pad] bf16
    int tid = threadIdx.x, lane = tid & 63, wave = tid >> 6;   // wave 0..7
    int g = lane >> 4, c = lane & 15;

    // 256 blocks: xcd = bid&7 owns 4 heads; p = pair index 0..7.
    int bid = blockIdx.x;                // 0..255
    int xcd = bid & 7, r = bid >> 3;     // r 0..31
    int bh = xcd * 4 + (r & 3);          // 0..31
    int p = r >> 2;                      // 0..7
    int b = bh >> 4, h = bh & 15;

    const bf16_t* Kb = KV + (size_t)b * SEQ * 5120 + h * DQK;   // + s*5120
    const bf16_t* Vb = VT + (size_t)bh * 128 * SEQ;
    char* ldsPw = ldsP + wave * (16 * 176);

    // K staging map: 1536 chunks of 16B over 512 threads (3 issues);
    // source chunk XORed so linear LDS + swizzled read composes to identity.
    size_t soff[3];
    #pragma unroll
    for (int i2 = 0; i2 < 3; ++i2) {
        int id = i2 * 512 + tid;
        int row = id / 24, ch = id - row * 24;
        soff[i2] = (size_t)row * 10240 + (ch ^ (row & 7)) * 16;
    }
    // V staging map: 1024 chunks over 512 threads (2 issues).
    size_t voff[2];
    #pragma unroll
    for (int i2 = 0; i2 < 2; ++i2) {
        int id = i2 * 512 + tid;
        int row = id >> 3, ch = id & 7;
        voff[i2] = (size_t)row * (SEQ * 2) + (ch ^ (row & 7)) * 16;
    }
    const float sc = 0.0721687836f * 1.44269504f;   // 1/sqrt(192) * log2(e)

    bf16x8 vones;
    #pragma unroll
    for (int j = 0; j < 8; ++j) vones[j] = (bf16_t)1.0f;

    #pragma unroll 1
    for (int pass = 0; pass < 2; ++pass) {
        int qt = pass ? p : (15 - p);        // heavy first, then light
        int q0 = qt * 128;
        int nt = 2 * qt + 2;
        int tdiag = 2 * qt + (wave >> 2);    // this wave's diagonal tile

        // Q fragments: lane (g,c) holds Q[row=q0+wave*16+c][k=kk*32+g*8+0..7]
        bf16x8 qf[6];
        {
            int qrow = q0 + wave * 16 + c;
            const bf16_t* qn = Qf + (size_t)(b * SEQ + qrow) * 3072 + h * DNOPE + g * 8;
            #pragma unroll
            for (int kk = 0; kk < 4; ++kk) qf[kk] = *(const bf16x8*)(qn + kk * 32);
            const bf16_t* qr = Qf + (size_t)(b * SEQ + qrow) * 3072 + 2048 + h * DROPE + g * 8;
            qf[4] = *(const bf16x8*)(qr);
            qf[5] = *(const bf16x8*)(qr + 32);
        }
        float m_run[4];
        f32x4 accO[9] = {};                  // [8] = running row-sum (ones column)
        #pragma unroll
        for (int i = 0; i < 4; ++i) m_run[i] = -3.0e38f;

        // prologue: stage tile 0 into buffer 0
        {
            const char* Kt = (const char*)(Kb);
            #pragma unroll
            for (int i2 = 0; i2 < 3; ++i2)
                GLDS16(Kt + soff[i2], ldsK + i2 * 8192 + wave * 1024);
            const char* Vt = (const char*)Vb;
            #pragma unroll
            for (int i2 = 0; i2 < 2; ++i2)
                GLDS16(Vt + voff[i2], ldsV + i2 * 8192 + wave * 1024);
        }
        __syncthreads();

        #pragma unroll 1
        for (int t = 0; t < nt; ++t) {
            int cur = t & 1;
            // issue next tile's staging into the other buffer (overlaps compute)
            if (t + 1 < nt) {
                int nxt = cur ^ 1;
                const char* Kt = (const char*)(Kb + (size_t)(t + 1) * 64 * 5120);
                #pragma unroll
                for (int i2 = 0; i2 < 3; ++i2)
                    GLDS16(Kt + soff[i2], ldsK + nxt * 24576 + i2 * 8192 + wave * 1024);
                const char* Vt = (const char*)Vb + (size_t)(t + 1) * 128;
                #pragma unroll
                for (int i2 = 0; i2 < 2; ++i2)
                    GLDS16(Vt + voff[i2], ldsV + nxt * 16384 + i2 * 8192 + wave * 1024);
            }

            if (t <= tdiag) {                // wave-uniform; no barrier inside
                bool diag = (t == tdiag);
                const char* ldsKc = ldsK + cur * 24576;
                const char* ldsVc = ldsV + cur * 16384;

                // QK^T: 16 q-rows x 64 k
                f32x4 accS[4] = {};
                __builtin_amdgcn_s_setprio(1);
                #pragma unroll
                for (int kk = 0; kk < 6; ++kk) {
                    int kb = kk * 64 + g * 16;
                    #pragma unroll
                    for (int n = 0; n < 4; ++n) {
                        int row = n * 16 + c;
                        bf16x8 kf = *(const bf16x8*)(ldsKc + row * 384 + (kb ^ ((row & 7) << 4)));
                        accS[n] = __builtin_amdgcn_mfma_f32_16x16x32_bf16(qf[kk], kf, accS[n], 0, 0, 0);
                    }
                }
                __builtin_amdgcn_s_setprio(0);

                // scale + causal mask (diag tile: in-tile row offset = (wave&3)*16)
                #pragma unroll
                for (int n = 0; n < 4; ++n)
                    #pragma unroll
                    for (int i = 0; i < 4; ++i) {
                        float v = accS[n][i] * sc;
                        if (diag && (n * 16 + c > (wave & 3) * 16 + g * 4 + i)) v = -1e30f;
                        accS[n][i] = v;
                    }
                // row max; sum comes free via ones-column MFMA
                float mx[4];
                #pragma unroll
                for (int i = 0; i < 4; ++i) {
                    float m2 = fmaxf(fmaxf(accS[0][i], accS[1][i]), fmaxf(accS[2][i], accS[3][i]));
                    #pragma unroll
                    for (int d = 1; d < 16; d <<= 1) m2 = fmaxf(m2, __shfl_xor(m2, d, 64));
                    mx[i] = m2;
                }
                bool nore = __all((mx[0] <= m_run[0] + 8.f) & (mx[1] <= m_run[1] + 8.f) &
                                  (mx[2] <= m_run[2] + 8.f) & (mx[3] <= m_run[3] + 8.f));
                if (nore) {
                    #pragma unroll
                    for (int i = 0; i < 4; ++i)
                        #pragma unroll
                        for (int n = 0; n < 4; ++n)
                            accS[n][i] = exp2f(accS[n][i] - m_run[i]);
                } else {
                    #pragma unroll
                    for (int i = 0; i < 4; ++i) {
                        float mnew = fmaxf(m_run[i], mx[i]);
                        float alpha = exp2f(m_run[i] - mnew);
                        m_run[i] = mnew;
                        #pragma unroll
                        for (int n = 0; n < 4; ++n)
                            accS[n][i] = exp2f(accS[n][i] - mnew);
                        #pragma unroll
                        for (int n = 0; n < 9; ++n) accO[n][i] *= alpha;
                    }
                }
                // P (C-frag) -> per-wave LDS -> A-frag
                #pragma unroll
                for (int n = 0; n < 4; ++n)
                    #pragma unroll
                    for (int i = 0; i < 4; ++i)
                        *(bf16_t*)(ldsPw + (g * 4 + i) * 176 + (n * 16 + c) * 2) = (bf16_t)accS[n][i];
                bf16x8 pf0 = *(const bf16x8*)(ldsPw + c * 176 + g * 16);
                bf16x8 pf1 = *(const bf16x8*)(ldsPw + c * 176 + 64 + g * 16);

                // PV: V from LDS (swizzled read), plus ones-column for row-sum
                __builtin_amdgcn_s_setprio(1);
                #pragma unroll
                for (int n = 0; n < 8; ++n) {
                    int row = n * 16 + c;
                    bf16x8 vf0 = *(const bf16x8*)(ldsVc + row * 128 + ((g * 16) ^ ((c & 7) << 4)));
                    bf16x8 vf1 = *(const bf16x8*)(ldsVc + row * 128 + ((64 + g * 16) ^ ((c & 7) << 4)));
                    accO[n] = __builtin_amdgcn_mfma_f32_16x16x32_bf16(pf0, vf0, accO[n], 0, 0, 0);
                    accO[n] = __builtin_amdgcn_mfma_f32_16x16x32_bf16(pf1, vf1, accO[n], 0, 0, 0);
                }
                accO[8] = __builtin_amdgcn_mfma_f32_16x16x32_bf16(pf0, vones, accO[8], 0, 0, 0);
                accO[8] = __builtin_amdgcn_mfma_f32_16x16x32_bf16(pf1, vones, accO[8], 0, 0, 0);
                __builtin_amdgcn_s_setprio(0);
            }
            // one barrier per tile: waits vmcnt(0) (next tile staged) and
            // ensures all waves are done reading buf cur before it's re-staged
            __syncthreads();
        }
        // write O, normalizing by the ones-column running sum
        float inv_l[4];
        #pragma unroll
        for (int i = 0; i < 4; ++i) inv_l[i] = 1.0f / accO[8][i];
        #pragma unroll
        for (int n = 0; n < 8; ++n) {
            int gcol = h * 128 + n * 16 + c;
            #pragma unroll
            for (int i = 0; i < 4; ++i) {
                int mrow = b * SEQ + q0 + wave * 16 + g * 4 + i;
                O[(size_t)mrow * 2048 + gcol] = (bf16_t)(accO[n][i] * inv_l[i]);
            }
        }
        __syncthreads();   // pass boundary: LDS reuse safety
    }
}

// ---------------- launch ----------------

extern "C" void kernel_launch(void* const* d_in, const int* in_sizes, int n_in,
                              void* d_out, int out_size, void* d_ws, size_t ws_size,
                              hipStream_t stream) {
    const float* x     = (const float*)d_in[0];
    const float* freqs = (const float*)d_in[1];
    const float* w_kv  = (const float*)d_in[2];
    const float* g_kv  = (const float*)d_in[3];
    const float* w_k   = (const float*)d_in[4];
    const float* w_v   = (const float*)d_in[5];
    const float* w_qn  = (const float*)d_in[6];
    const float* w_qr  = (const float*)d_in[7];
    const float* w_o   = (const float*)d_in[8];
    float* out = (float*)d_out;

    char* ws = (char*)d_ws;
    size_t off = 0;
    auto alloc = [&](size_t bytes) { char* p = ws + off; off += (bytes + 255) & ~(size_t)255; return p; };
    bf16_t* xb     = (bf16_t*)alloc((size_t)MROWS * DMODEL * 2);
    bf16_t* wkvT   = (bf16_t*)alloc((size_t)RDIM * DMODEL * 2);
    bf16_t* wkvwT  = (bf16_t*)alloc((size_t)5120 * RDIM * 2);
    bf16_t* wqT    = (bf16_t*)alloc((size_t)3072 * DMODEL * 2);
    bf16_t* woT    = (bf16_t*)alloc((size_t)DMODEL * DMODEL * 2);
    float*  kvf    = (float*) alloc((size_t)MROWS * RDIM * 4);
    bf16_t* kvb    = (bf16_t*)alloc((size_t)MROWS * RDIM * 2);
    bf16_t* kvout  = (bf16_t*)alloc((size_t)MROWS * 5120 * 2);
    bf16_t* qfull  = (bf16_t*)alloc((size_t)MROWS * 3072 * 2);
    bf16_t* vt     = (bf16_t*)alloc((size_t)32 * 128 * SEQ * 2);
    bf16_t* attno  = (bf16_t*)alloc((size_t)MROWS * 2048 * 2);
    float*  costab = (float*) alloc((size_t)SEQ * 32 * 4);
    float*  sintab = (float*) alloc((size_t)SEQ * 32 * 4);

    // prep
    cast_x_kernel<<<(MROWS * DMODEL / 4) / 256, 256, 0, stream>>>(x, xb);
    wtrans_kernel<<<dim3(RDIM / 32, DMODEL / 32), 256, 0, stream>>>(w_kv, wkvT, DMODEL, RDIM);
    wtrans_kernel<<<dim3(3072 / 32, RDIM / 32), 256, 0, stream>>>(w_k, wkvwT, RDIM, 3072);
    wtrans_kernel<<<dim3(2048 / 32, RDIM / 32), 256, 0, stream>>>(w_v, wkvwT + (size_t)3072 * RDIM, RDIM, 2048);
    wtrans_kernel<<<dim3(2048 / 32, DMODEL / 32), 256, 0, stream>>>(w_qn, wqT, DMODEL, 2048);
    wtrans_kernel<<<dim3(1024 / 32, DMODEL / 32), 256, 0, stream>>>(w_qr, wqT + (size_t)2048 * DMODEL, DMODEL, 1024);
    wtrans_kernel<<<dim3(2048 / 32, DMODEL / 32), 256, 0, stream>>>(w_o, woT, DMODEL, 2048);
    rope_table_kernel<<<(SEQ * 32) / 256, 256, 0, stream>>>(freqs, costab, sintab);

    // G1: kv_pre = x @ w_kv   (f32 out for rmsnorm)
    gemm_bt<float, 0><<<dim3(RDIM / 128, MROWS / 128), 256, 0, stream>>>(xb, wkvT, kvf, MROWS, RDIM, DMODEL, nullptr, nullptr);
    rmsnorm_kernel<<<MROWS, 256, 0, stream>>>(kvf, g_kv, kvb);
    // G2: [k_full | v] = kv @ [w_k | w_v], rope fused on k-rope cols
    gemm_bt<bf16_t, 1><<<dim3(5120 / 128, MROWS / 128), 256, 0, stream>>>(kvb, wkvwT, kvout, MROWS, 5120, RDIM, costab, sintab);
    // G3: [q_nope | q_rope] = x @ [w_qn | w_qr], rope fused on cols >= 2048
    gemm_bt<bf16_t, 2><<<dim3(3072 / 128, MROWS / 128), 256, 0, stream>>>(xb, wqT, qfull, MROWS, 3072, DMODEL, costab, sintab);

    // v transpose only (k/q consumed in native layouts)
    pack_v_kernel<<<32 * 32, 256, 0, stream>>>(kvout, vt);

    // attention (256 blocks x 8 waves, 2 q-tiles per block, 36 KV tiles per CU)
    attn_kernel<<<256, 512, 0, stream>>>(qfull, kvout, vt, attno);

    // G4: out = attn_out @ w_o   (f32 out)
    gemm_bt<float, 0><<<dim3(2048 / 128, MROWS / 128), 256, 0, stream>>>(attno, woT, out, MROWS, 2048, DMODEL, nullptr, nullptr);
}

// Round 11
// 304.399 us; speedup vs baseline: 1.4329x; 1.0649x over previous
//
#include <hip/hip_runtime.h>

typedef __bf16 bf16_t;
typedef bf16_t bf16x8 __attribute__((ext_vector_type(8)));
typedef bf16_t bf16x4v __attribute__((ext_vector_type(4)));
typedef float f32x4 __attribute__((ext_vector_type(4)));

#define GLDS16(g, l) __builtin_amdgcn_global_load_lds( \
    (const __attribute__((address_space(1))) void*)(g), \
    (__attribute__((address_space(3))) void*)(l), 16, 0, 0)

// Problem constants
#define BB 2
#define SEQ 2048
#define DMODEL 2048
#define RDIM 512
#define NH 16
#define DNOPE 128
#define DROPE 64
#define DVDIM 128
#define MROWS 4096           // BB*SEQ
#define DQK 192              // DNOPE+DROPE

// ---------------- prep kernels ----------------

__global__ __launch_bounds__(256) void cast_x_kernel(const float* __restrict__ x,
                                                     bf16_t* __restrict__ xb) {
    int idx = blockIdx.x * 256 + threadIdx.x;
    float4 v = ((const float4*)x)[idx];
    bf16x4v o;
    o[0] = (bf16_t)v.x; o[1] = (bf16_t)v.y; o[2] = (bf16_t)v.z; o[3] = (bf16_t)v.w;
    ((bf16x4v*)xb)[idx] = o;
}

// W (K x N) f32 -> WT (N x K) bf16, tiled transpose
__global__ __launch_bounds__(256) void wtrans_kernel(const float* __restrict__ W,
                                                     bf16_t* __restrict__ WT,
                                                     int K, int N) {
    __shared__ float t[32][33];
    int n0 = blockIdx.x * 32, k0 = blockIdx.y * 32;
    int tx = threadIdx.x & 31, ty = threadIdx.x >> 5;  // ty 0..7
    #pragma unroll
    for (int i = 0; i < 4; ++i)
        t[ty + i*8][tx] = W[(size_t)(k0 + ty + i*8) * N + n0 + tx];
    __syncthreads();
    #pragma unroll
    for (int i = 0; i < 4; ++i)
        WT[(size_t)(n0 + ty + i*8) * K + k0 + tx] = (bf16_t)t[tx][ty + i*8];
}

__global__ __launch_bounds__(256) void rope_table_kernel(const float* __restrict__ freqs,
                                                         float* __restrict__ costab,
                                                         float* __restrict__ sintab) {
    int idx = blockIdx.x * 256 + threadIdx.x;   // SEQ*32 exact
    float f = freqs[idx];
    costab[idx] = cosf(f);
    sintab[idx] = sinf(f);
}

__global__ __launch_bounds__(256) void rmsnorm_kernel(const float* __restrict__ kvf,
                                                      const float* __restrict__ gkv,
                                                      bf16_t* __restrict__ kvb) {
    int m = blockIdx.x;
    int tid = threadIdx.x;
    const float* rowp = kvf + (size_t)m * RDIM;
    float2 v = *(const float2*)(rowp + tid * 2);
    float ss = v.x * v.x + v.y * v.y;
    #pragma unroll
    for (int d = 1; d < 64; d <<= 1) ss += __shfl_xor(ss, d, 64);
    __shared__ float red[4];
    if ((tid & 63) == 0) red[tid >> 6] = ss;
    __syncthreads();
    float tot = red[0] + red[1] + red[2] + red[3];
    float scale = rsqrtf(tot * (1.0f / RDIM) + 1e-6f);
    bf16_t* orow = kvb + (size_t)m * RDIM;
    orow[tid*2]     = (bf16_t)(v.x * scale * gkv[tid*2]);
    orow[tid*2 + 1] = (bf16_t)(v.y * scale * gkv[tid*2 + 1]);
}

// ---------------- GEMM: C(MxN) = A(MxK) * Bt(NxK)^T, bf16 in --------
// 128x128 tile, BK=64, 4 waves (2x2), global_load_lds staging with XOR swizzle.
// EPI: 0 = plain store; 1 = kvout (rope cols n<3072 with n%192>=128);
//      2 = qfull (rope cols n>=2048);
//      3 = merged kv_pre|q: cols<512 -> f32 C (stride 512); cols>=512 ->
//          bf16 C2 (stride 3072, rope on qcol>=2048). Rope pairs in lanes (c,c^1).

template<typename OutT, int EPI>
__global__ __launch_bounds__(256, 2) void gemm_bt(const bf16_t* __restrict__ A,
                                                  const bf16_t* __restrict__ Bt,
                                                  OutT* __restrict__ C,
                                                  int M, int N, int K,
                                                  const float* __restrict__ costab,
                                                  const float* __restrict__ sintab,
                                                  bf16_t* __restrict__ C2) {
    __shared__ __align__(16) char ldsA[128 * 128];   // 128 rows x 128B (64 bf16)
    __shared__ __align__(16) char ldsB[128 * 128];
    int tid = threadIdx.x;
    int lane = tid & 63, wave = tid >> 6;
    int n0 = blockIdx.x * 128, m0 = blockIdx.y * 128;
    int wr = wave >> 1, wc = wave & 1;
    int g = lane >> 4, c = lane & 15;
    f32x4 acc[4][4] = {};

    int srow = tid >> 3;         // 0..31: row within 4KB staging slab
    int sch = tid & 7;           // chunk (16B) within 128B row

    int nkt = K >> 6;
    for (int kt = 0; kt < nkt; ++kt) {
        int k0 = kt << 6;
        #pragma unroll
        for (int j = 0; j < 4; ++j) {
            int row = j * 32 + srow;
            int csrc = sch ^ (row & 7);     // pre-swizzled source chunk
            const char* gA = (const char*)(A + (size_t)(m0 + row) * K + k0) + csrc * 16;
            const char* gB = (const char*)(Bt + (size_t)(n0 + row) * K + k0) + csrc * 16;
            char* lA = ldsA + j * 4096 + wave * 1024;
            char* lB = ldsB + j * 4096 + wave * 1024;
            GLDS16(gA, lA);
            GLDS16(gB, lB);
        }
        __syncthreads();
        #pragma unroll
        for (int kk = 0; kk < 2; ++kk) {
            int kb = kk * 64 + g * 16;      // byte offset within row
            bf16x8 aF[4], bF[4];
            #pragma unroll
            for (int m = 0; m < 4; ++m) {
                int row = wr * 64 + m * 16 + c;
                aF[m] = *(const bf16x8*)(ldsA + row * 128 + (kb ^ ((row & 7) << 4)));
            }
            #pragma unroll
            for (int n = 0; n < 4; ++n) {
                int row = wc * 64 + n * 16 + c;
                bF[n] = *(const bf16x8*)(ldsB + row * 128 + (kb ^ ((row & 7) << 4)));
            }
            #pragma unroll
            for (int m = 0; m < 4; ++m)
                #pragma unroll
                for (int n = 0; n < 4; ++n)
                    acc[m][n] = __builtin_amdgcn_mfma_f32_16x16x32_bf16(aF[m], bF[n], acc[m][n], 0, 0, 0);
        }
        __syncthreads();
    }
    // epilogue: C/D layout col=lane&15, row=(lane>>4)*4+i
    #pragma unroll
    for (int m = 0; m < 4; ++m) {
        int grow0 = m0 + wr * 64 + m * 16 + g * 4;
        #pragma unroll
        for (int n = 0; n < 4; ++n) {
            int gcol = n0 + wc * 64 + n * 16 + c;
            if (EPI == 3) {
                if (gcol < 512) {
                    #pragma unroll
                    for (int i = 0; i < 4; ++i)
                        C[(size_t)(grow0 + i) * 512 + gcol] = (OutT)acc[m][n][i];
                } else {
                    int qcol = gcol - 512;
                    if (qcol >= 2048) {
                        int j = ((qcol - 2048) & 63) >> 1;
                        bool even = (c & 1) == 0;
                        #pragma unroll
                        for (int i = 0; i < 4; ++i) {
                            float v = acc[m][n][i];
                            float pv = __shfl_xor(v, 1, 64);
                            int s = (grow0 + i) & (SEQ - 1);
                            float cs = costab[s * 32 + j], sn = sintab[s * 32 + j];
                            float o = even ? (v * cs - pv * sn) : (pv * sn + v * cs);
                            C2[(size_t)(grow0 + i) * 3072 + qcol] = (bf16_t)o;
                        }
                    } else {
                        #pragma unroll
                        for (int i = 0; i < 4; ++i)
                            C2[(size_t)(grow0 + i) * 3072 + qcol] = (bf16_t)acc[m][n][i];
                    }
                }
            } else {
                bool rope = false;
                int j = 0;
                if (EPI == 1) {
                    rope = (gcol < 3072) && ((gcol % 192) >= 128);
                    j = ((gcol % 192) - 128) >> 1;
                } else if (EPI == 2) {
                    rope = (gcol >= 2048);
                    j = ((gcol - 2048) & 63) >> 1;
                }
                if (EPI != 0 && rope) {
                    bool even = (c & 1) == 0;
                    #pragma unroll
                    for (int i = 0; i < 4; ++i) {
                        float v = acc[m][n][i];
                        float pv = __shfl_xor(v, 1, 64);
                        int s = (grow0 + i) & (SEQ - 1);
                        float cs = costab[s * 32 + j], sn = sintab[s * 32 + j];
                        float o = even ? (v * cs - pv * sn) : (pv * sn + v * cs);
                        C[(size_t)(grow0 + i) * N + gcol] = (OutT)o;
                    }
                } else {
                    #pragma unroll
                    for (int i = 0; i < 4; ++i)
                        C[(size_t)(grow0 + i) * N + gcol] = (OutT)acc[m][n][i];
                }
            }
        }
    }
}

// v part of kvout -> vt [BH][128][SEQ]  (transposed for PV B-fragments)
__global__ __launch_bounds__(256) void pack_v_kernel(const bf16_t* __restrict__ kvout,
                                                     bf16_t* __restrict__ vt) {
    __shared__ bf16_t t[64][144];
    int blk = blockIdx.x;                 // 32 bh * 32 stiles
    int bh = blk >> 5, st = blk & 31;
    int s0 = st * 64;
    int b = bh >> 4, h = bh & 15;
    int tid = threadIdx.x;
    #pragma unroll
    for (int i = 0; i < 4; ++i) {
        int id = i * 256 + tid;           // 1024: 64 rows x 16 chunks
        int row = id >> 4, ch = id & 15;
        bf16x8 v = *(const bf16x8*)(kvout + (size_t)(b * SEQ + s0 + row) * 5120 + 3072 + h * 128 + ch * 8);
        *(bf16x8*)&t[row][ch * 8] = v;
    }
    __syncthreads();
    #pragma unroll
    for (int i = 0; i < 4; ++i) {
        int id = i * 256 + tid;           // 1024: 128 dv x 8 chunks
        int dv = id >> 3, sc = id & 7;
        bf16x8 v;
        #pragma unroll
        for (int jj = 0; jj < 8; ++jj) v[jj] = t[sc * 8 + jj][dv];
        *(bf16x8*)(vt + ((size_t)bh * 128 + dv) * SEQ + s0 + sc * 8) = v;
    }
}

// ---------------- flash attention v8 ----------------
// Q direct from qfull [M][3072]; K direct from kvout [M][5120] (h*192 slice);
// VT: [BH][128][S]; O: [M][2048] (col=h*128+dv).
// 256 blocks (1/CU) x 8 waves. Each block: TWO 128-row q-tiles (heavy 15-p,
// then light p) -> 36 KV tiles/CU. THREE-deep staging pipeline with counted
// vmcnt + raw s_barrier (T3/T4): per iter {vmcnt(5); s_barrier; issue
// stage(t+2); compute(t)} -- staging loads stay in flight across barriers.
// sc folded into Q fragments (bf16 Q: no extra rounding). Ones-column row-sum;
// defer-max (THR=8).

__global__ __launch_bounds__(512, 2) void attn_kernel(const bf16_t* __restrict__ Qf,
                                                      const bf16_t* __restrict__ KV,
                                                      const bf16_t* __restrict__ VT,
                                                      bf16_t* __restrict__ O) {
    __shared__ __align__(16) char ldsK[3 * 64 * 384];   // 3-buf [64][192] bf16, swizzled content
    __shared__ __align__(16) char ldsV[3 * 128 * 128];  // 3-buf [128 dv][64 s] bf16, swizzled content
    __shared__ __align__(16) char ldsP[8 * 16 * 176];   // per-wave [16][64+24pad] bf16
    int tid = threadIdx.x, lane = tid & 63, wave = tid >> 6;   // wave 0..7
    int g = lane >> 4, c = lane & 15;

    // 256 blocks: xcd = bid&7 owns 4 heads; p = pair index 0..7.
    int bid = blockIdx.x;                // 0..255
    int xcd = bid & 7, r = bid >> 3;     // r 0..31
    int bh = xcd * 4 + (r & 3);          // 0..31
    int p = r >> 2;                      // 0..7
    int b = bh >> 4, h = bh & 15;

    const bf16_t* Kb = KV + (size_t)b * SEQ * 5120 + h * DQK;   // + s*5120
    const bf16_t* Vb = VT + (size_t)bh * 128 * SEQ;
    char* ldsPw = ldsP + wave * (16 * 176);

    // K staging map: 1536 chunks of 16B over 512 threads (3 issues);
    // source chunk XORed so linear LDS + swizzled read composes to identity.
    size_t soff[3];
    #pragma unroll
    for (int i2 = 0; i2 < 3; ++i2) {
        int id = i2 * 512 + tid;
        int row = id / 24, ch = id - row * 24;
        soff[i2] = (size_t)row * 10240 + (ch ^ (row & 7)) * 16;
    }
    // V staging map: 1024 chunks over 512 threads (2 issues).
    size_t voff[2];
    #pragma unroll
    for (int i2 = 0; i2 < 2; ++i2) {
        int id = i2 * 512 + tid;
        int row = id >> 3, ch = id & 7;
        voff[i2] = (size_t)row * (SEQ * 2) + (ch ^ (row & 7)) * 16;
    }
    const float sc = 0.0721687836f * 1.44269504f;   // 1/sqrt(192) * log2(e)

    bf16x8 vones;
    #pragma unroll
    for (int j = 0; j < 8; ++j) vones[j] = (bf16_t)1.0f;

    // stage tile t into buffer buf (5 glds per thread = 5 vm ops per wave)
    auto stage = [&](int t, int buf) {
        const char* Kt = (const char*)(Kb + (size_t)t * 64 * 5120);
        #pragma unroll
        for (int i2 = 0; i2 < 3; ++i2)
            GLDS16(Kt + soff[i2], ldsK + buf * 24576 + i2 * 8192 + wave * 1024);
        const char* Vt = (const char*)Vb + (size_t)t * 128;
        #pragma unroll
        for (int i2 = 0; i2 < 2; ++i2)
            GLDS16(Vt + voff[i2], ldsV + buf * 16384 + i2 * 8192 + wave * 1024);
    };

    #pragma unroll 1
    for (int pass = 0; pass < 2; ++pass) {
        int qt = pass ? p : (15 - p);        // heavy first, then light
        int q0 = qt * 128;
        int nt = 2 * qt + 2;
        int tdiag = 2 * qt + (wave >> 2);    // this wave's diagonal tile

        // Q fragments, pre-scaled by sc (Q already bf16 -> no extra rounding)
        bf16x8 qf[6];
        {
            int qrow = q0 + wave * 16 + c;
            const bf16_t* qn = Qf + (size_t)(b * SEQ + qrow) * 3072 + h * DNOPE + g * 8;
            #pragma unroll
            for (int kk = 0; kk < 4; ++kk) qf[kk] = *(const bf16x8*)(qn + kk * 32);
            const bf16_t* qr = Qf + (size_t)(b * SEQ + qrow) * 3072 + 2048 + h * DROPE + g * 8;
            qf[4] = *(const bf16x8*)(qr);
            qf[5] = *(const bf16x8*)(qr + 32);
            #pragma unroll
            for (int kk = 0; kk < 6; ++kk)
                #pragma unroll
                for (int j = 0; j < 8; ++j)
                    qf[kk][j] = (bf16_t)((float)qf[kk][j] * sc);
        }
        float m_run[4];
        f32x4 accO[9] = {};                  // [8] = running row-sum (ones column)
        #pragma unroll
        for (int i = 0; i < 4; ++i) m_run[i] = -3.0e38f;

        // prologue: 2 tiles in flight
        stage(0, 0);
        stage(1, 1);

        #pragma unroll 1
        for (int t = 0; t < nt; ++t) {
            int cur = t - (t / 3) * 3;       // t % 3
            // counted wait: stage(t) complete (stage(t+1)'s 5 loads may remain)
            if (t + 1 < nt) asm volatile("s_waitcnt vmcnt(5)" ::: "memory");
            else            asm volatile("s_waitcnt vmcnt(0)" ::: "memory");
            __builtin_amdgcn_s_barrier();    // raw barrier: no compiler drain
            __builtin_amdgcn_sched_barrier(0);
            asm volatile("" ::: "memory");
            // issue stage(t+2) into buf freed by the barrier above
            if (t + 2 < nt) stage(t + 2, (t + 2) % 3);

            if (t <= tdiag) {                // wave-uniform; no barrier inside
                bool diag = (t == tdiag);
                const char* ldsKc = ldsK + cur * 24576;
                const char* ldsVc = ldsV + cur * 16384;

                // QK^T: 16 q-rows x 64 k (scores already in log2 units via qf)
                f32x4 accS[4] = {};
                __builtin_amdgcn_s_setprio(1);
                #pragma unroll
                for (int kk = 0; kk < 6; ++kk) {
                    int kb = kk * 64 + g * 16;
                    #pragma unroll
                    for (int n = 0; n < 4; ++n) {
                        int row = n * 16 + c;
                        bf16x8 kf = *(const bf16x8*)(ldsKc + row * 384 + (kb ^ ((row & 7) << 4)));
                        accS[n] = __builtin_amdgcn_mfma_f32_16x16x32_bf16(qf[kk], kf, accS[n], 0, 0, 0);
                    }
                }
                __builtin_amdgcn_s_setprio(0);

                // causal mask on diag tile only (in-tile row offset = (wave&3)*16)
                if (diag) {
                    #pragma unroll
                    for (int n = 0; n < 4; ++n)
                        #pragma unroll
                        for (int i = 0; i < 4; ++i)
                            if (n * 16 + c > (wave & 3) * 16 + g * 4 + i) accS[n][i] = -1e30f;
                }
                // row max; sum comes free via ones-column MFMA
                float mx[4];
                #pragma unroll
                for (int i = 0; i < 4; ++i) {
                    float m2 = fmaxf(fmaxf(accS[0][i], accS[1][i]), fmaxf(accS[2][i], accS[3][i]));
                    #pragma unroll
                    for (int d = 1; d < 16; d <<= 1) m2 = fmaxf(m2, __shfl_xor(m2, d, 64));
                    mx[i] = m2;
                }
                bool nore = __all((mx[0] <= m_run[0] + 8.f) & (mx[1] <= m_run[1] + 8.f) &
                                  (mx[2] <= m_run[2] + 8.f) & (mx[3] <= m_run[3] + 8.f));
                if (nore) {
                    #pragma unroll
                    for (int i = 0; i < 4; ++i)
                        #pragma unroll
                        for (int n = 0; n < 4; ++n)
                            accS[n][i] = exp2f(accS[n][i] - m_run[i]);
                } else {
                    #pragma unroll
                    for (int i = 0; i < 4; ++i) {
                        float mnew = fmaxf(m_run[i], mx[i]);
                        float alpha = exp2f(m_run[i] - mnew);
                        m_run[i] = mnew;
                        #pragma unroll
                        for (int n = 0; n < 4; ++n)
                            accS[n][i] = exp2f(accS[n][i] - mnew);
                        #pragma unroll
                        for (int n = 0; n < 9; ++n) accO[n][i] *= alpha;
                    }
                }
                // P (C-frag) -> per-wave LDS -> A-frag (wave-private: no barrier)
                #pragma unroll
                for (int n = 0; n < 4; ++n)
                    #pragma unroll
                    for (int i = 0; i < 4; ++i)
                        *(bf16_t*)(ldsPw + (g * 4 + i) * 176 + (n * 16 + c) * 2) = (bf16_t)accS[n][i];
                bf16x8 pf0 = *(const bf16x8*)(ldsPw + c * 176 + g * 16);
                bf16x8 pf1 = *(const bf16x8*)(ldsPw + c * 176 + 64 + g * 16);

                // PV: V from LDS (swizzled read), plus ones-column for row-sum
                __builtin_amdgcn_s_setprio(1);
                #pragma unroll
                for (int n = 0; n < 8; ++n) {
                    int row = n * 16 + c;
                    bf16x8 vf0 = *(const bf16x8*)(ldsVc + row * 128 + ((g * 16) ^ ((c & 7) << 4)));
                    bf16x8 vf1 = *(const bf16x8*)(ldsVc + row * 128 + ((64 + g * 16) ^ ((c & 7) << 4)));
                    accO[n] = __builtin_amdgcn_mfma_f32_16x16x32_bf16(pf0, vf0, accO[n], 0, 0, 0);
                    accO[n] = __builtin_amdgcn_mfma_f32_16x16x32_bf16(pf1, vf1, accO[n], 0, 0, 0);
                }
                accO[8] = __builtin_amdgcn_mfma_f32_16x16x32_bf16(pf0, vones, accO[8], 0, 0, 0);
                accO[8] = __builtin_amdgcn_mfma_f32_16x16x32_bf16(pf1, vones, accO[8], 0, 0, 0);
                __builtin_amdgcn_s_setprio(0);
            }
        }
        // write O, normalizing by the ones-column running sum
        float inv_l[4];
        #pragma unroll
        for (int i = 0; i < 4; ++i) inv_l[i] = 1.0f / accO[8][i];
        #pragma unroll
        for (int n = 0; n < 8; ++n) {
            int gcol = h * 128 + n * 16 + c;
            #pragma unroll
            for (int i = 0; i < 4; ++i) {
                int mrow = b * SEQ + q0 + wave * 16 + g * 4 + i;
                O[(size_t)mrow * 2048 + gcol] = (bf16_t)(accO[n][i] * inv_l[i]);
            }
        }
        __syncthreads();   // pass boundary: full drain + LDS reuse safety
    }
}

// ---------------- launch ----------------

extern "C" void kernel_launch(void* const* d_in, const int* in_sizes, int n_in,
                              void* d_out, int out_size, void* d_ws, size_t ws_size,
                              hipStream_t stream) {
    const float* x     = (const float*)d_in[0];
    const float* freqs = (const float*)d_in[1];
    const float* w_kv  = (const float*)d_in[2];
    const float* g_kv  = (const float*)d_in[3];
    const float* w_k   = (const float*)d_in[4];
    const float* w_v   = (const float*)d_in[5];
    const float* w_qn  = (const float*)d_in[6];
    const float* w_qr  = (const float*)d_in[7];
    const float* w_o   = (const float*)d_in[8];
    float* out = (float*)d_out;

    char* ws = (char*)d_ws;
    size_t off = 0;
    auto alloc = [&](size_t bytes) { char* p = ws + off; off += (bytes + 255) & ~(size_t)255; return p; };
    bf16_t* xb     = (bf16_t*)alloc((size_t)MROWS * DMODEL * 2);
    bf16_t* wqkT   = (bf16_t*)alloc((size_t)3584 * DMODEL * 2);   // [wkv|wqn|wqr] N x K
    bf16_t* wkvwT  = (bf16_t*)alloc((size_t)5120 * RDIM * 2);
    bf16_t* woT    = (bf16_t*)alloc((size_t)DMODEL * DMODEL * 2);
    float*  kvf    = (float*) alloc((size_t)MROWS * RDIM * 4);
    bf16_t* kvb    = (bf16_t*)alloc((size_t)MROWS * RDIM * 2);
    bf16_t* kvout  = (bf16_t*)alloc((size_t)MROWS * 5120 * 2);
    bf16_t* qfull  = (bf16_t*)alloc((size_t)MROWS * 3072 * 2);
    bf16_t* vt     = (bf16_t*)alloc((size_t)32 * 128 * SEQ * 2);
    bf16_t* attno  = (bf16_t*)alloc((size_t)MROWS * 2048 * 2);
    float*  costab = (float*) alloc((size_t)SEQ * 32 * 4);
    float*  sintab = (float*) alloc((size_t)SEQ * 32 * 4);

    // prep
    cast_x_kernel<<<(MROWS * DMODEL / 4) / 256, 256, 0, stream>>>(x, xb);
    wtrans_kernel<<<dim3(RDIM / 32, DMODEL / 32), 256, 0, stream>>>(w_kv, wqkT, DMODEL, RDIM);
    wtrans_kernel<<<dim3(2048 / 32, DMODEL / 32), 256, 0, stream>>>(w_qn, wqkT + (size_t)512 * DMODEL, DMODEL, 2048);
    wtrans_kernel<<<dim3(1024 / 32, DMODEL / 32), 256, 0, stream>>>(w_qr, wqkT + (size_t)2560 * DMODEL, DMODEL, 1024);
    wtrans_kernel<<<dim3(3072 / 32, RDIM / 32), 256, 0, stream>>>(w_k, wkvwT, RDIM, 3072);
    wtrans_kernel<<<dim3(2048 / 32, RDIM / 32), 256, 0, stream>>>(w_v, wkvwT + (size_t)3072 * RDIM, RDIM, 2048);
    wtrans_kernel<<<dim3(2048 / 32, DMODEL / 32), 256, 0, stream>>>(w_o, woT, DMODEL, 2048);
    rope_table_kernel<<<(SEQ * 32) / 256, 256, 0, stream>>>(freqs, costab, sintab);

    // G13: merged [kv_pre | q_nope | q_rope] = x @ [w_kv | w_qn | w_qr]
    gemm_bt<float, 3><<<dim3(3584 / 128, MROWS / 128), 256, 0, stream>>>(
        xb, wqkT, kvf, MROWS, 3584, DMODEL, costab, sintab, qfull);
    rmsnorm_kernel<<<MROWS, 256, 0, stream>>>(kvf, g_kv, kvb);
    // G2: [k_full | v] = kv @ [w_k | w_v], rope fused on k-rope cols
    gemm_bt<bf16_t, 1><<<dim3(5120 / 128, MROWS / 128), 256, 0, stream>>>(
        kvb, wkvwT, kvout, MROWS, 5120, RDIM, costab, sintab, nullptr);

    // v transpose only (k/q consumed in native layouts)
    pack_v_kernel<<<32 * 32, 256, 0, stream>>>(kvout, vt);

    // attention (256 blocks x 8 waves, 2 q-tiles per block, 36 KV tiles per CU)
    attn_kernel<<<256, 512, 0, stream>>>(qfull, kvout, vt, attno);

    // G4: out = attn_out @ w_o   (f32 out)
    gemm_bt<float, 0><<<dim3(2048 / 128, MROWS / 128), 256, 0, stream>>>(
        attno, woT, out, MROWS, 2048, DMODEL, nullptr, nullptr, nullptr);
}

// Round 12
// 276.369 us; speedup vs baseline: 1.5782x; 1.1014x over previous
//
#include <hip/hip_runtime.h>

typedef __bf16 bf16_t;
typedef bf16_t bf16x8 __attribute__((ext_vector_type(8)));
typedef bf16_t bf16x4v __attribute__((ext_vector_type(4)));
typedef float f32x4 __attribute__((ext_vector_type(4)));

#define GLDS16(g, l) __builtin_amdgcn_global_load_lds( \
    (const __attribute__((address_space(1))) void*)(g), \
    (__attribute__((address_space(3))) void*)(l), 16, 0, 0)

// Problem constants
#define BB 2
#define SEQ 2048
#define DMODEL 2048
#define RDIM 512
#define NH 16
#define DNOPE 128
#define DROPE 64
#define DVDIM 128
#define MROWS 4096           // BB*SEQ
#define DQK 192              // DNOPE+DROPE
#define KSTRIDE 3072         // kvout row stride (k_full only; v goes to vt)

// ---------------- prep kernels ----------------

__global__ __launch_bounds__(256) void cast_x_kernel(const float* __restrict__ x,
                                                     bf16_t* __restrict__ xb) {
    int idx = blockIdx.x * 256 + threadIdx.x;
    float4 v = ((const float4*)x)[idx];
    bf16x4v o;
    o[0] = (bf16_t)v.x; o[1] = (bf16_t)v.y; o[2] = (bf16_t)v.z; o[3] = (bf16_t)v.w;
    ((bf16x4v*)xb)[idx] = o;
}

// Multi-source W (K x Nsrc) f32 -> WT (N x K) bf16 transpose; up to 3 sources
// concatenated along output-N. Region select by n0 is block-uniform (boundaries
// multiples of 32).
__global__ __launch_bounds__(256) void wtrans3_kernel(const float* __restrict__ W0,
                                                      const float* __restrict__ W1,
                                                      const float* __restrict__ W2,
                                                      int N0, int N1, int N2,
                                                      int b1, int b2,
                                                      bf16_t* __restrict__ WT, int K) {
    __shared__ float t[32][33];
    int n0 = blockIdx.x * 32, k0 = blockIdx.y * 32;
    const float* W; int Nsrc, cb;
    if (n0 < b1)      { W = W0; Nsrc = N0; cb = 0; }
    else if (n0 < b2) { W = W1; Nsrc = N1; cb = b1; }
    else              { W = W2; Nsrc = N2; cb = b2; }
    int col = n0 - cb;
    int tx = threadIdx.x & 31, ty = threadIdx.x >> 5;  // ty 0..7
    #pragma unroll
    for (int i = 0; i < 4; ++i)
        t[ty + i*8][tx] = W[(size_t)(k0 + ty + i*8) * Nsrc + col + tx];
    __syncthreads();
    #pragma unroll
    for (int i = 0; i < 4; ++i)
        WT[(size_t)(n0 + ty + i*8) * K + k0 + tx] = (bf16_t)t[tx][ty + i*8];
}

__global__ __launch_bounds__(256) void rope_table_kernel(const float* __restrict__ freqs,
                                                         float* __restrict__ costab,
                                                         float* __restrict__ sintab) {
    int idx = blockIdx.x * 256 + threadIdx.x;   // SEQ*32 exact
    float f = freqs[idx];
    costab[idx] = cosf(f);
    sintab[idx] = sinf(f);
}

__global__ __launch_bounds__(256) void rmsnorm_kernel(const float* __restrict__ kvf,
                                                      const float* __restrict__ gkv,
                                                      bf16_t* __restrict__ kvb) {
    int m = blockIdx.x;
    int tid = threadIdx.x;
    const float* rowp = kvf + (size_t)m * RDIM;
    float2 v = *(const float2*)(rowp + tid * 2);
    float ss = v.x * v.x + v.y * v.y;
    #pragma unroll
    for (int d = 1; d < 64; d <<= 1) ss += __shfl_xor(ss, d, 64);
    __shared__ float red[4];
    if ((tid & 63) == 0) red[tid >> 6] = ss;
    __syncthreads();
    float tot = red[0] + red[1] + red[2] + red[3];
    float scale = rsqrtf(tot * (1.0f / RDIM) + 1e-6f);
    bf16_t* orow = kvb + (size_t)m * RDIM;
    orow[tid*2]     = (bf16_t)(v.x * scale * gkv[tid*2]);
    orow[tid*2 + 1] = (bf16_t)(v.y * scale * gkv[tid*2 + 1]);
}

// ---------------- GEMM: C(MxN) = A(MxK) * Bt(NxK)^T, bf16 in --------
// 128x128 tile, BK=64, 4 waves (2x2), global_load_lds staging with XOR swizzle.
// EPI: 0 = plain store;
//      1 = kvout/vt: cols<3072 -> kvout [M][3072] (rope on n%192>=128);
//          cols>=3072 -> vt [BH][128][SEQ] transposed (4 contiguous s per lane);
//      3 = merged kv_pre|q: cols<512 -> f32 C (stride 512); cols>=512 ->
//          bf16 C2 (stride 3072, rope on qcol>=2048). Rope pairs in lanes (c,c^1).

template<typename OutT, int EPI>
__global__ __launch_bounds__(256, 3) void gemm_bt(const bf16_t* __restrict__ A,
                                                  const bf16_t* __restrict__ Bt,
                                                  OutT* __restrict__ C,
                                                  int M, int N, int K,
                                                  const float* __restrict__ costab,
                                                  const float* __restrict__ sintab,
                                                  bf16_t* __restrict__ C2) {
    __shared__ __align__(16) char ldsA[128 * 128];   // 128 rows x 128B (64 bf16)
    __shared__ __align__(16) char ldsB[128 * 128];
    int tid = threadIdx.x;
    int lane = tid & 63, wave = tid >> 6;
    int n0 = blockIdx.x * 128, m0 = blockIdx.y * 128;
    int wr = wave >> 1, wc = wave & 1;
    int g = lane >> 4, c = lane & 15;
    f32x4 acc[4][4] = {};

    int srow = tid >> 3;         // 0..31: row within 4KB staging slab
    int sch = tid & 7;           // chunk (16B) within 128B row

    int nkt = K >> 6;
    for (int kt = 0; kt < nkt; ++kt) {
        int k0 = kt << 6;
        #pragma unroll
        for (int j = 0; j < 4; ++j) {
            int row = j * 32 + srow;
            int csrc = sch ^ (row & 7);     // pre-swizzled source chunk
            const char* gA = (const char*)(A + (size_t)(m0 + row) * K + k0) + csrc * 16;
            const char* gB = (const char*)(Bt + (size_t)(n0 + row) * K + k0) + csrc * 16;
            char* lA = ldsA + j * 4096 + wave * 1024;
            char* lB = ldsB + j * 4096 + wave * 1024;
            GLDS16(gA, lA);
            GLDS16(gB, lB);
        }
        __syncthreads();
        #pragma unroll
        for (int kk = 0; kk < 2; ++kk) {
            int kb = kk * 64 + g * 16;      // byte offset within row
            bf16x8 aF[4], bF[4];
            #pragma unroll
            for (int m = 0; m < 4; ++m) {
                int row = wr * 64 + m * 16 + c;
                aF[m] = *(const bf16x8*)(ldsA + row * 128 + (kb ^ ((row & 7) << 4)));
            }
            #pragma unroll
            for (int n = 0; n < 4; ++n) {
                int row = wc * 64 + n * 16 + c;
                bF[n] = *(const bf16x8*)(ldsB + row * 128 + (kb ^ ((row & 7) << 4)));
            }
            #pragma unroll
            for (int m = 0; m < 4; ++m)
                #pragma unroll
                for (int n = 0; n < 4; ++n)
                    acc[m][n] = __builtin_amdgcn_mfma_f32_16x16x32_bf16(aF[m], bF[n], acc[m][n], 0, 0, 0);
        }
        __syncthreads();
    }
    // epilogue: C/D layout col=lane&15, row=(lane>>4)*4+i
    #pragma unroll
    for (int m = 0; m < 4; ++m) {
        int grow0 = m0 + wr * 64 + m * 16 + g * 4;
        #pragma unroll
        for (int n = 0; n < 4; ++n) {
            int gcol = n0 + wc * 64 + n * 16 + c;
            if (EPI == 1) {
                if (gcol < 3072) {
                    bool rope = (gcol % 192) >= 128;
                    if (rope) {
                        int j = ((gcol % 192) - 128) >> 1;
                        bool even = (c & 1) == 0;
                        #pragma unroll
                        for (int i = 0; i < 4; ++i) {
                            float v = acc[m][n][i];
                            float pv = __shfl_xor(v, 1, 64);
                            int s = (grow0 + i) & (SEQ - 1);
                            float cs = costab[s * 32 + j], sn = sintab[s * 32 + j];
                            float o = even ? (v * cs - pv * sn) : (pv * sn + v * cs);
                            C[(size_t)(grow0 + i) * KSTRIDE + gcol] = (OutT)o;
                        }
                    } else {
                        #pragma unroll
                        for (int i = 0; i < 4; ++i)
                            C[(size_t)(grow0 + i) * KSTRIDE + gcol] = (OutT)acc[m][n][i];
                    }
                } else {
                    // v-part -> vt [BH][128][SEQ], 4 contiguous s per lane
                    int vcol = gcol - 3072;
                    int hh = vcol >> 7, dv = vcol & 127;
                    int bb = grow0 >> 11, s = grow0 & (SEQ - 1);
                    bf16x4v o;
                    #pragma unroll
                    for (int i = 0; i < 4; ++i) o[i] = (bf16_t)acc[m][n][i];
                    *(bf16x4v*)(C2 + ((size_t)(bb * NH + hh) * 128 + dv) * SEQ + s) = o;
                }
            } else if (EPI == 3) {
                if (gcol < 512) {
                    #pragma unroll
                    for (int i = 0; i < 4; ++i)
                        C[(size_t)(grow0 + i) * 512 + gcol] = (OutT)acc[m][n][i];
                } else {
                    int qcol = gcol - 512;
                    if (qcol >= 2048) {
                        int j = ((qcol - 2048) & 63) >> 1;
                        bool even = (c & 1) == 0;
                        #pragma unroll
                        for (int i = 0; i < 4; ++i) {
                            float v = acc[m][n][i];
                            float pv = __shfl_xor(v, 1, 64);
                            int s = (grow0 + i) & (SEQ - 1);
                            float cs = costab[s * 32 + j], sn = sintab[s * 32 + j];
                            float o = even ? (v * cs - pv * sn) : (pv * sn + v * cs);
                            C2[(size_t)(grow0 + i) * 3072 + qcol] = (bf16_t)o;
                        }
                    } else {
                        #pragma unroll
                        for (int i = 0; i < 4; ++i)
                            C2[(size_t)(grow0 + i) * 3072 + qcol] = (bf16_t)acc[m][n][i];
                    }
                }
            } else {
                #pragma unroll
                for (int i = 0; i < 4; ++i)
                    C[(size_t)(grow0 + i) * N + gcol] = (OutT)acc[m][n][i];
            }
        }
    }
}

// ---------------- flash attention v9 ----------------
// Q direct from qfull [M][3072]; K direct from kvout [M][3072] (h*192 slice);
// VT: [BH][128][S]; O: [M][2048] (col=h*128+dv).
// 256 blocks (1/CU) x 8 waves. TWO 128-row q-tiles per block (heavy 15-p then
// light p) -> 36 KV tiles/CU. 3-deep staging, counted vmcnt + raw s_barrier.
// Cheap-max: per-lane max vs m_run+8 first; full shfl reduce only on fail.
// Ones-column row-sum; sc folded into Q fragments.

__global__ __launch_bounds__(512, 2) void attn_kernel(const bf16_t* __restrict__ Qf,
                                                      const bf16_t* __restrict__ KV,
                                                      const bf16_t* __restrict__ VT,
                                                      bf16_t* __restrict__ O) {
    __shared__ __align__(16) char ldsK[3 * 64 * 384];   // 3-buf [64][192] bf16, swizzled content
    __shared__ __align__(16) char ldsV[3 * 128 * 128];  // 3-buf [128 dv][64 s] bf16, swizzled content
    __shared__ __align__(16) char ldsP[8 * 16 * 176];   // per-wave [16][64+24pad] bf16
    int tid = threadIdx.x, lane = tid & 63, wave = tid >> 6;   // wave 0..7
    int g = lane >> 4, c = lane & 15;

    // 256 blocks: xcd = bid&7 owns 4 heads; p = pair index 0..7.
    int bid = blockIdx.x;                // 0..255
    int xcd = bid & 7, r = bid >> 3;     // r 0..31
    int bh = xcd * 4 + (r & 3);          // 0..31
    int p = r >> 2;                      // 0..7
    int b = bh >> 4, h = bh & 15;

    const bf16_t* Kb = KV + (size_t)b * SEQ * KSTRIDE + h * DQK;   // + s*3072
    const bf16_t* Vb = VT + (size_t)bh * 128 * SEQ;
    char* ldsPw = ldsP + wave * (16 * 176);

    // K staging map: 1536 chunks of 16B over 512 threads (3 issues);
    // source chunk XORed so linear LDS + swizzled read composes to identity.
    size_t soff[3];
    #pragma unroll
    for (int i2 = 0; i2 < 3; ++i2) {
        int id = i2 * 512 + tid;
        int row = id / 24, ch = id - row * 24;
        soff[i2] = (size_t)row * (KSTRIDE * 2) + (ch ^ (row & 7)) * 16;
    }
    // V staging map: 1024 chunks over 512 threads (2 issues).
    size_t voff[2];
    #pragma unroll
    for (int i2 = 0; i2 < 2; ++i2) {
        int id = i2 * 512 + tid;
        int row = id >> 3, ch = id & 7;
        voff[i2] = (size_t)row * (SEQ * 2) + (ch ^ (row & 7)) * 16;
    }
    const float sc = 0.0721687836f * 1.44269504f;   // 1/sqrt(192) * log2(e)

    bf16x8 vones;
    #pragma unroll
    for (int j = 0; j < 8; ++j) vones[j] = (bf16_t)1.0f;

    // stage tile t into buffer buf (5 glds per thread = 5 vm ops per wave)
    auto stage = [&](int t, int buf) {
        const char* Kt = (const char*)Kb + (size_t)t * (64 * KSTRIDE * 2);
        #pragma unroll
        for (int i2 = 0; i2 < 3; ++i2)
            GLDS16(Kt + soff[i2], ldsK + buf * 24576 + i2 * 8192 + wave * 1024);
        const char* Vt = (const char*)Vb + (size_t)t * 128;
        #pragma unroll
        for (int i2 = 0; i2 < 2; ++i2)
            GLDS16(Vt + voff[i2], ldsV + buf * 16384 + i2 * 8192 + wave * 1024);
    };

    #pragma unroll 1
    for (int pass = 0; pass < 2; ++pass) {
        int qt = pass ? p : (15 - p);        // heavy first, then light
        int q0 = qt * 128;
        int nt = 2 * qt + 2;
        int tdiag = 2 * qt + (wave >> 2);    // this wave's diagonal tile

        // Q fragments, pre-scaled by sc (Q already bf16 -> no extra rounding)
        bf16x8 qf[6];
        {
            int qrow = q0 + wave * 16 + c;
            const bf16_t* qn = Qf + (size_t)(b * SEQ + qrow) * 3072 + h * DNOPE + g * 8;
            #pragma unroll
            for (int kk = 0; kk < 4; ++kk) qf[kk] = *(const bf16x8*)(qn + kk * 32);
            const bf16_t* qr = Qf + (size_t)(b * SEQ + qrow) * 3072 + 2048 + h * DROPE + g * 8;
            qf[4] = *(const bf16x8*)(qr);
            qf[5] = *(const bf16x8*)(qr + 32);
            #pragma unroll
            for (int kk = 0; kk < 6; ++kk)
                #pragma unroll
                for (int j = 0; j < 8; ++j)
                    qf[kk][j] = (bf16_t)((float)qf[kk][j] * sc);
        }
        float m_run[4];
        f32x4 accO[9] = {};                  // [8] = running row-sum (ones column)
        #pragma unroll
        for (int i = 0; i < 4; ++i) m_run[i] = -3.0e38f;

        // prologue: 2 tiles in flight
        stage(0, 0);
        stage(1, 1);

        #pragma unroll 1
        for (int t = 0; t < nt; ++t) {
            int cur = t - (t / 3) * 3;       // t % 3
            // counted wait: stage(t) complete (stage(t+1)'s 5 loads may remain)
            if (t + 1 < nt) asm volatile("s_waitcnt vmcnt(5)" ::: "memory");
            else            asm volatile("s_waitcnt vmcnt(0)" ::: "memory");
            __builtin_amdgcn_s_barrier();    // raw barrier: no compiler drain
            __builtin_amdgcn_sched_barrier(0);
            asm volatile("" ::: "memory");
            // issue stage(t+2) into buf freed by the barrier above
            if (t + 2 < nt) stage(t + 2, (t + 2) % 3);

            if (t <= tdiag) {                // wave-uniform; no barrier inside
                bool diag = (t == tdiag);
                const char* ldsKc = ldsK + cur * 24576;
                const char* ldsVc = ldsV + cur * 16384;

                // QK^T: 16 q-rows x 64 k (scores already in log2 units via qf)
                f32x4 accS[4] = {};
                __builtin_amdgcn_s_setprio(1);
                #pragma unroll
                for (int kk = 0; kk < 6; ++kk) {
                    int kb = kk * 64 + g * 16;
                    #pragma unroll
                    for (int n = 0; n < 4; ++n) {
                        int row = n * 16 + c;
                        bf16x8 kf = *(const bf16x8*)(ldsKc + row * 384 + (kb ^ ((row & 7) << 4)));
                        accS[n] = __builtin_amdgcn_mfma_f32_16x16x32_bf16(qf[kk], kf, accS[n], 0, 0, 0);
                    }
                }
                __builtin_amdgcn_s_setprio(0);

                // causal mask on diag tile only (in-tile row offset = (wave&3)*16)
                if (diag) {
                    #pragma unroll
                    for (int n = 0; n < 4; ++n)
                        #pragma unroll
                        for (int i = 0; i < 4; ++i)
                            if (n * 16 + c > (wave & 3) * 16 + g * 4 + i) accS[n][i] = -1e30f;
                }
                // cheap-max: per-lane max vs m_run+8 (valid bound: lane max <=
                // row max). Full shfl reduce only when some lane exceeds.
                float mloc[4];
                #pragma unroll
                for (int i = 0; i < 4; ++i)
                    mloc[i] = fmaxf(fmaxf(accS[0][i], accS[1][i]), fmaxf(accS[2][i], accS[3][i]));
                bool cheap = __all((mloc[0] <= m_run[0] + 8.f) & (mloc[1] <= m_run[1] + 8.f) &
                                   (mloc[2] <= m_run[2] + 8.f) & (mloc[3] <= m_run[3] + 8.f));
                if (cheap) {
                    #pragma unroll
                    for (int i = 0; i < 4; ++i)
                        #pragma unroll
                        for (int n = 0; n < 4; ++n)
                            accS[n][i] = exp2f(accS[n][i] - m_run[i]);
                } else {
                    #pragma unroll
                    for (int i = 0; i < 4; ++i) {
                        float m2 = mloc[i];
                        #pragma unroll
                        for (int d = 1; d < 16; d <<= 1) m2 = fmaxf(m2, __shfl_xor(m2, d, 64));
                        float mnew = fmaxf(m_run[i], m2);
                        float alpha = exp2f(m_run[i] - mnew);
                        m_run[i] = mnew;
                        #pragma unroll
                        for (int n = 0; n < 4; ++n)
                            accS[n][i] = exp2f(accS[n][i] - mnew);
                        #pragma unroll
                        for (int n = 0; n < 9; ++n) accO[n][i] *= alpha;
                    }
                }
                // P (C-frag) -> per-wave LDS -> A-frag (wave-private: no barrier)
                #pragma unroll
                for (int n = 0; n < 4; ++n)
                    #pragma unroll
                    for (int i = 0; i < 4; ++i)
                        *(bf16_t*)(ldsPw + (g * 4 + i) * 176 + (n * 16 + c) * 2) = (bf16_t)accS[n][i];
                bf16x8 pf0 = *(const bf16x8*)(ldsPw + c * 176 + g * 16);
                bf16x8 pf1 = *(const bf16x8*)(ldsPw + c * 176 + 64 + g * 16);

                // PV: V from LDS (swizzled read), plus ones-column for row-sum
                __builtin_amdgcn_s_setprio(1);
                #pragma unroll
                for (int n = 0; n < 8; ++n) {
                    int row = n * 16 + c;
                    bf16x8 vf0 = *(const bf16x8*)(ldsVc + row * 128 + ((g * 16) ^ ((c & 7) << 4)));
                    bf16x8 vf1 = *(const bf16x8*)(ldsVc + row * 128 + ((64 + g * 16) ^ ((c & 7) << 4)));
                    accO[n] = __builtin_amdgcn_mfma_f32_16x16x32_bf16(pf0, vf0, accO[n], 0, 0, 0);
                    accO[n] = __builtin_amdgcn_mfma_f32_16x16x32_bf16(pf1, vf1, accO[n], 0, 0, 0);
                }
                accO[8] = __builtin_amdgcn_mfma_f32_16x16x32_bf16(pf0, vones, accO[8], 0, 0, 0);
                accO[8] = __builtin_amdgcn_mfma_f32_16x16x32_bf16(pf1, vones, accO[8], 0, 0, 0);
                __builtin_amdgcn_s_setprio(0);
            }
        }
        // write O, normalizing by the ones-column running sum
        float inv_l[4];
        #pragma unroll
        for (int i = 0; i < 4; ++i) inv_l[i] = 1.0f / accO[8][i];
        #pragma unroll
        for (int n = 0; n < 8; ++n) {
            int gcol = h * 128 + n * 16 + c;
            #pragma unroll
            for (int i = 0; i < 4; ++i) {
                int mrow = b * SEQ + q0 + wave * 16 + g * 4 + i;
                O[(size_t)mrow * 2048 + gcol] = (bf16_t)(accO[n][i] * inv_l[i]);
            }
        }
        __syncthreads();   // pass boundary: full drain + LDS reuse safety
    }
}

// ---------------- launch ----------------

extern "C" void kernel_launch(void* const* d_in, const int* in_sizes, int n_in,
                              void* d_out, int out_size, void* d_ws, size_t ws_size,
                              hipStream_t stream) {
    const float* x     = (const float*)d_in[0];
    const float* freqs = (const float*)d_in[1];
    const float* w_kv  = (const float*)d_in[2];
    const float* g_kv  = (const float*)d_in[3];
    const float* w_k   = (const float*)d_in[4];
    const float* w_v   = (const float*)d_in[5];
    const float* w_qn  = (const float*)d_in[6];
    const float* w_qr  = (const float*)d_in[7];
    const float* w_o   = (const float*)d_in[8];
    float* out = (float*)d_out;

    char* ws = (char*)d_ws;
    size_t off = 0;
    auto alloc = [&](size_t bytes) { char* p = ws + off; off += (bytes + 255) & ~(size_t)255; return p; };
    bf16_t* xb     = (bf16_t*)alloc((size_t)MROWS * DMODEL * 2);
    bf16_t* wqkT   = (bf16_t*)alloc((size_t)3584 * DMODEL * 2);   // [wkv|wqn|wqr] N x K
    bf16_t* wkvwT  = (bf16_t*)alloc((size_t)5120 * RDIM * 2);     // [wk|wv] N x K
    bf16_t* woT    = (bf16_t*)alloc((size_t)DMODEL * DMODEL * 2);
    float*  kvf    = (float*) alloc((size_t)MROWS * RDIM * 4);
    bf16_t* kvb    = (bf16_t*)alloc((size_t)MROWS * RDIM * 2);
    bf16_t* kvout  = (bf16_t*)alloc((size_t)MROWS * KSTRIDE * 2); // k_full only
    bf16_t* qfull  = (bf16_t*)alloc((size_t)MROWS * 3072 * 2);
    bf16_t* vt     = (bf16_t*)alloc((size_t)32 * 128 * SEQ * 2);
    bf16_t* attno  = (bf16_t*)alloc((size_t)MROWS * 2048 * 2);
    float*  costab = (float*) alloc((size_t)SEQ * 32 * 4);
    float*  sintab = (float*) alloc((size_t)SEQ * 32 * 4);

    // prep (4 dispatches)
    cast_x_kernel<<<(MROWS * DMODEL / 4) / 256, 256, 0, stream>>>(x, xb);
    // wqkT = [w_kv | w_qn | w_qr]^T  (K=2048, N=3584, boundaries 512/2560)
    wtrans3_kernel<<<dim3(3584 / 32, DMODEL / 32), 256, 0, stream>>>(
        w_kv, w_qn, w_qr, 512, 2048, 1024, 512, 2560, wqkT, DMODEL);
    // wkvwT = [w_k | w_v]^T  (K=512, N=5120, boundary 3072)
    wtrans3_kernel<<<dim3(5120 / 32, RDIM / 32), 256, 0, stream>>>(
        w_k, w_v, w_v, 3072, 2048, 2048, 3072, 5120, wkvwT, RDIM);
    // woT (K=2048, N=2048)
    wtrans3_kernel<<<dim3(2048 / 32, DMODEL / 32), 256, 0, stream>>>(
        w_o, w_o, w_o, 2048, 2048, 2048, 2048, 4096, woT, DMODEL);
    rope_table_kernel<<<(SEQ * 32) / 256, 256, 0, stream>>>(freqs, costab, sintab);

    // G13: merged [kv_pre | q_nope | q_rope] = x @ [w_kv | w_qn | w_qr]
    gemm_bt<float, 3><<<dim3(3584 / 128, MROWS / 128), 256, 0, stream>>>(
        xb, wqkT, kvf, MROWS, 3584, DMODEL, costab, sintab, qfull);
    rmsnorm_kernel<<<MROWS, 256, 0, stream>>>(kvf, g_kv, kvb);
    // G2: [k_full -> kvout (rope) | v -> vt (transposed)] = kv @ [w_k | w_v]
    gemm_bt<bf16_t, 1><<<dim3(5120 / 128, MROWS / 128), 256, 0, stream>>>(
        kvb, wkvwT, kvout, MROWS, 5120, RDIM, costab, sintab, vt);

    // attention (256 blocks x 8 waves, 2 q-tiles per block, 36 KV tiles per CU)
    attn_kernel<<<256, 512, 0, stream>>>(qfull, kvout, vt, attno);

    // G4: out = attn_out @ w_o   (f32 out)
    gemm_bt<float, 0><<<dim3(2048 / 128, MROWS / 128), 256, 0, stream>>>(
        attno, woT, out, MROWS, 2048, DMODEL, nullptr, nullptr, nullptr);
}